// Round 12
// baseline (151.281 us; speedup 1.0000x reference)
//
#include <hip/hip_runtime.h>
#include <hip/hip_bf16.h>

// Shapes
#define Bz 32
#define Tz 256
#define Fz 64
#define Dz 768
#define Sz 768
#define Hz 256
#define NHz 4
#define HDz 64
#define BTz 8192  // B*T
#define NPAIRPAD 1024
#define QKPAD 72   // bf16 units; 144B row stride: 2-way bank alias (free)
#define VTPAD 264
#define PLPAD 72   // PV 64-key chunk

typedef __attribute__((ext_vector_type(8))) short short8v;
typedef __attribute__((ext_vector_type(8))) unsigned short ushort8v;
typedef __attribute__((ext_vector_type(4))) float f32x4;

__device__ inline unsigned short f2bf_rne(float x) {
    unsigned u = __float_as_uint(x);
    unsigned r = (u + 0x7fffu + ((u >> 16) & 1u)) >> 16;
    return (unsigned short)r;
}
__device__ inline float bf2f(unsigned short x) {
    return __uint_as_float(((unsigned)x) << 16);
}
__device__ inline short8v expand8(unsigned bits) {
    short8v r;
    #pragma unroll
    for (int j = 0; j < 8; ++j)
        r[j] = (bits & (1u << j)) ? (short)0x3f80 : (short)0;
    return r;
}

// ===========================================================================
// Device bodies
// ===========================================================================

// Unified LDS-staged MFMA GEMM body (unchanged from R11).
template <int BM, int BN, bool OUTBF16, int B2MODE>
__device__ __forceinline__ void gemm2_body(
    unsigned short* __restrict__ smem,
    const unsigned short* __restrict__ A,
    const unsigned short* __restrict__ Bt,
    const float* __restrict__ bias, const float* __restrict__ bias2,
    void* __restrict__ Cv, int M, int N, int K, int bx, int by, int tid)
{
    constexpr int WC = BN / 64;
    constexpr int WR = 4 / WC;
    constexpr int RW = BM / WR;
    constexpr int MT = RW / 16;
    constexpr int NT = 4;
    unsigned short* As = smem;
    unsigned short* Bs = smem + BM * 40;
    const int lane = tid & 63, wave = tid >> 6;
    const int l15 = lane & 15, g = lane >> 4;
    const int wr = wave / WC, wc = wave % WC;
    const int row0 = by * BM, col0 = bx * BN;

    f32x4 acc[MT][NT] = {};

    for (int k0 = 0; k0 < K; k0 += 32) {
        __syncthreads();
        #pragma unroll
        for (int i = 0; i < BM * 4 / 256; ++i) {
            int e = tid + i * 256;
            int r = e >> 2, c8 = e & 3;
            *(ushort8v*)(As + r * 40 + c8 * 8) =
                *(const ushort8v*)(A + (size_t)(row0 + r) * K + k0 + c8 * 8);
        }
        #pragma unroll
        for (int i = 0; i < BN * 4 / 256; ++i) {
            int e = tid + i * 256;
            int n = e >> 2, c = e & 3;
            *(ushort8v*)(Bs + n * 40 + c * 8) =
                *(const ushort8v*)(Bt + (size_t)(col0 + n) * K + k0 + c * 8);
        }
        __syncthreads();

        short8v a[MT], b[NT];
        #pragma unroll
        for (int m = 0; m < MT; ++m)
            a[m] = *(const short8v*)(As + (wr * RW + m * 16 + l15) * 40 + g * 8);
        #pragma unroll
        for (int n = 0; n < NT; ++n)
            b[n] = *(const short8v*)(Bs + (wc * 64 + n * 16 + l15) * 40 + g * 8);
        #pragma unroll
        for (int m = 0; m < MT; ++m)
            #pragma unroll
            for (int n = 0; n < NT; ++n)
                acc[m][n] = __builtin_amdgcn_mfma_f32_16x16x32_bf16(a[m], b[n], acc[m][n], 0, 0, 0);
    }

    #pragma unroll
    for (int m = 0; m < MT; ++m) {
        #pragma unroll
        for (int rr = 0; rr < 4; ++rr) {
            int row = row0 + wr * RW + m * 16 + g * 4 + rr;
            #pragma unroll
            for (int n = 0; n < NT; ++n) {
                int col = col0 + wc * 64 + n * 16 + l15;
                float o = acc[m][n][rr];
                if (B2MODE == 2) {
                    o += (col < (N >> 1)) ? bias[col] : bias2[col - (N >> 1)];
                } else if (B2MODE != 3) {
                    o += bias[col];
                    if (B2MODE == 1) o += bias2[col];
                }
                if (OUTBF16) ((unsigned short*)Cv)[(size_t)row * N + col] = f2bf_rne(o);
                else         ((float*)Cv)[(size_t)row * N + col] = o;
            }
        }
    }
}

// selkv register GEMM: kvproj = inv_cnt ⊙ (Sel-bits @ PeWaT^T) + bkv.
// BM=64, BN=128, K=1024. NO LDS, NO barriers: A expanded from sel bits
// per-lane in registers; B fragments loaded 16B/lane from L2-resident PeWaT.
__device__ __forceinline__ void gemm_selkv_reg_body(
    const unsigned long long* __restrict__ sel,
    const unsigned short* __restrict__ Bt,     // PeWaT [512][1024]
    const float* __restrict__ rs,              // inv_cnt [8192]
    const float* __restrict__ bias,            // bkv [512]
    unsigned short* __restrict__ C,            // kvproj [8192][512]
    int bx, int by, int tid)
{
    const int lane = tid & 63, wave = tid >> 6;
    const int l15 = lane & 15, g = lane >> 4;
    const int wr = wave >> 1, wc = wave & 1;
    const int row0 = by * 64, col0 = bx * 128;

    const int rowA0 = row0 + wr * 32 + l15;
    const unsigned long long* selr0 = sel + (size_t)rowA0 * 16;
    const unsigned long long* selr1 = selr0 + 16 * 16;   // +16 rows
    const unsigned short* bptr[4];
    #pragma unroll
    for (int n = 0; n < 4; ++n)
        bptr[n] = Bt + (size_t)(col0 + wc * 64 + n * 16 + l15) * 1024 + g * 8;

    f32x4 acc[2][4] = {};

    for (int k0 = 0; k0 < 1024; k0 += 32) {
        const int word = k0 >> 6;
        const int shift = (k0 & 32) + g * 8;
        short8v a0 = expand8((unsigned)(selr0[word] >> shift) & 0xFFu);
        short8v a1 = expand8((unsigned)(selr1[word] >> shift) & 0xFFu);
        short8v bfr[4];
        #pragma unroll
        for (int n = 0; n < 4; ++n)
            bfr[n] = *(const short8v*)(bptr[n] + k0);
        #pragma unroll
        for (int n = 0; n < 4; ++n) {
            acc[0][n] = __builtin_amdgcn_mfma_f32_16x16x32_bf16(a0, bfr[n], acc[0][n], 0, 0, 0);
            acc[1][n] = __builtin_amdgcn_mfma_f32_16x16x32_bf16(a1, bfr[n], acc[1][n], 0, 0, 0);
        }
    }

    #pragma unroll
    for (int m = 0; m < 2; ++m) {
        #pragma unroll
        for (int rr = 0; rr < 4; ++rr) {
            int row = row0 + wr * 32 + m * 16 + g * 4 + rr;
            float s = rs[row];
            #pragma unroll
            for (int n = 0; n < 4; ++n) {
                int col = col0 + wc * 64 + n * 16 + l15;
                C[(size_t)row * 512 + col] = f2bf_rne(acc[m][n][rr] * s + bias[col]);
            }
        }
    }
}

// Register GEMM (no LDS/barriers): C = A @ Bt^T + bias -> bf16.
// BM=64, BN=128. A bf16 [M][K], Bt bf16 [N][K], both fragment-loaded direct.
__device__ __forceinline__ void gemm_reg_body(
    const unsigned short* __restrict__ A,
    const unsigned short* __restrict__ Bt,
    const float* __restrict__ bias, unsigned short* __restrict__ C,
    int N, int K, int bx, int by, int tid)
{
    const int lane = tid & 63, wave = tid >> 6;
    const int l15 = lane & 15, g = lane >> 4;
    const int wr = wave >> 1, wc = wave & 1;
    const int row0 = by * 64, col0 = bx * 128;

    const unsigned short* aptr0 = A + (size_t)(row0 + wr * 32 + l15) * K + g * 8;
    const unsigned short* aptr1 = aptr0 + (size_t)16 * K;
    const unsigned short* bptr[4];
    #pragma unroll
    for (int n = 0; n < 4; ++n)
        bptr[n] = Bt + (size_t)(col0 + wc * 64 + n * 16 + l15) * K + g * 8;

    f32x4 acc[2][4] = {};

    for (int k0 = 0; k0 < K; k0 += 32) {
        short8v a0 = *(const short8v*)(aptr0 + k0);
        short8v a1 = *(const short8v*)(aptr1 + k0);
        short8v bfr[4];
        #pragma unroll
        for (int n = 0; n < 4; ++n)
            bfr[n] = *(const short8v*)(bptr[n] + k0);
        #pragma unroll
        for (int n = 0; n < 4; ++n) {
            acc[0][n] = __builtin_amdgcn_mfma_f32_16x16x32_bf16(a0, bfr[n], acc[0][n], 0, 0, 0);
            acc[1][n] = __builtin_amdgcn_mfma_f32_16x16x32_bf16(a1, bfr[n], acc[1][n], 0, 0, 0);
        }
    }

    #pragma unroll
    for (int m = 0; m < 2; ++m) {
        #pragma unroll
        for (int rr = 0; rr < 4; ++rr) {
            int row = row0 + wr * 32 + m * 16 + g * 4 + rr;
            #pragma unroll
            for (int n = 0; n < 4; ++n) {
                int col = col0 + wc * 64 + n * 16 + l15;
                C[(size_t)row * N + col] = f2bf_rne(acc[m][n][rr] + bias[col]);
            }
        }
    }
}

// masking body
__device__ __forceinline__ void mask_body(
    const float* __restrict__ bd, const float* __restrict__ mp,
    unsigned short* __restrict__ safe_bf, float* __restrict__ stoch_out,
    unsigned long long* __restrict__ mask64, int bid, int tid)
{
    int idx = bid * 256 + tid;
    float x = bd[idx];
    float p = mp[idx];
    unsigned xb = __float_as_uint(x);
    bool valid = ((xb & 0x7fffffffu) <= 0x7f800000u);
    bool st = (p < 0.3f) && valid;
    bool sv = valid && !st;
    safe_bf[idx] = sv ? f2bf_rne(x) : 0;
    stoch_out[idx] = st ? 1.0f : 0.0f;
    unsigned long long m = __ballot(sv);
    if ((tid & 63) == 0) mask64[idx >> 6] = m;
}

// pooled body
__device__ __forceinline__ void pooled_body(
    unsigned short* __restrict__ smem,
    const float* __restrict__ E, const float* __restrict__ W_sap,
    const float* __restrict__ b_sap, float* __restrict__ pooled, int bid, int tid)
{
    float* colmean = (float*)smem;
    float* red = colmean + Sz;
    for (int s = tid; s < Sz; s += 256) {
        float a = 0.0f;
        #pragma unroll 8
        for (int f = 0; f < Fz; ++f) a += E[(size_t)f * Sz + s];
        colmean[s] = a * (1.0f / 64.0f);
    }
    __syncthreads();
    const int hl = tid & 63, sg = tid >> 6;
    const int h = bid * 64 + hl;
    float acc = 0.0f;
    #pragma unroll 4
    for (int s = sg; s < Sz; s += 4)
        acc = fmaf(colmean[s], W_sap[(size_t)s * Hz + h], acc);
    red[sg * 64 + hl] = acc;
    __syncthreads();
    if (sg == 0)
        pooled[h] = b_sap[h] + ((red[hl] + red[64 + hl]) + (red[128 + hl] + red[192 + hl]));
}

// wbuild body
__device__ __forceinline__ void wbuild_body(
    unsigned short* __restrict__ smem,
    const unsigned long long* __restrict__ mask64,
    const unsigned int* __restrict__ plist,
    unsigned long long* __restrict__ sel, float* __restrict__ inv_cnt,
    int bid, int tid)
{
    unsigned int* pl = (unsigned int*)smem;
    for (int i = tid; i < NPAIRPAD; i += 256) pl[i] = plist[1 + i];
    __syncthreads();
    const int np = (int)plist[0];
    const int btl = tid >> 4, w = tid & 15;
    const int bt = bid * 16 + btl;
    unsigned long long m = mask64[bt];
    unsigned long long word = 0ull;
    int pbase = w * 64;
    int jmax = min(64, np - pbase);
    for (int j = 0; j < jmax; ++j) {
        unsigned ij = pl[pbase + j];
        unsigned long long bit = (m >> (ij >> 6)) & (m >> (ij & 63)) & 1ull;
        word |= bit << j;
    }
    sel[(size_t)bt * 16 + w] = word;
    int c = __popcll(word);
    #pragma unroll
    for (int s = 1; s < 16; s <<= 1) c += __shfl_xor(c, s);
    if (w == 0) inv_cnt[bt] = c > 0 ? 1.0f / (float)c : 0.0f;
}

// pe body
__device__ __forceinline__ void pe_body(
    const float* __restrict__ pair_emb, const unsigned int* __restrict__ plist,
    unsigned short* __restrict__ Pe, int p, int t)
{
    int np = (int)plist[0];
    if (p < np) {
        unsigned ij = plist[1 + p];
        const float* src = pair_emb + (size_t)ij * Dz;
        #pragma unroll
        for (int c = 0; c < 3; ++c)
            Pe[(size_t)p * Dz + t + c * 256] = f2bf_rne(src[t + c * 256]);
    } else {
        #pragma unroll
        for (int c = 0; c < 3; ++c)
            Pe[(size_t)p * Dz + t + c * 256] = 0;
    }
}

// meanheads body
__device__ __forceinline__ void meanheads_body(
    const unsigned short* __restrict__ probs, float* __restrict__ out3,
    int bid, int tid)
{
    int idx = bid * 256 + tid;
    int tk8 = idx & 31;
    int btq = idx >> 5;
    int b = btq >> 8, tq = btq & 255;
    float acc[8] = {};
    #pragma unroll
    for (int h = 0; h < 4; ++h) {
        int bh = b * 4 + h;
        ushort8v p = *(const ushort8v*)&probs[(((size_t)bh * Tz + tq) << 8) + tk8 * 8];
        #pragma unroll
        for (int j = 0; j < 8; ++j) acc[j] += bf2f(p[j]) * 0.25f;
    }
    float* dst = out3 + ((size_t)btq << 8) + tk8 * 8;
    float4 o0 = {acc[0], acc[1], acc[2], acc[3]};
    float4 o1 = {acc[4], acc[5], acc[6], acc[7]};
    *(float4*)dst = o0;
    *(float4*)(dst + 4) = o1;
}

// final body
__device__ __forceinline__ void final_body(
    unsigned short* __restrict__ smem,
    const unsigned short* __restrict__ qBF, const unsigned short* __restrict__ pvb,
    const unsigned short* __restrict__ WoutT, const unsigned short* __restrict__ WWT,
    const float* __restrict__ bias, float* __restrict__ C, int bid, int tid)
{
    unsigned short* As = smem;
    unsigned short* Bs = smem + 64 * 40;
    const int lane = tid & 63, wave = tid >> 6;
    const int l15 = lane & 15, g = lane >> 4;
    const int row0 = bid * 64;

    f32x4 acc[4] = {};

    for (int ph = 0; ph < 2; ++ph) {
        const unsigned short* Am = ph == 0 ? qBF : pvb;
        const unsigned short* Bm = ph == 0 ? WoutT : WWT;
        for (int k0 = 0; k0 < 256; k0 += 32) {
            __syncthreads();
            {
                int r = tid >> 2, c8 = tid & 3;
                *(ushort8v*)(As + r * 40 + c8 * 8) =
                    *(const ushort8v*)(Am + (size_t)(row0 + r) * Hz + k0 + c8 * 8);
                *(ushort8v*)(Bs + r * 40 + c8 * 8) =
                    *(const ushort8v*)(Bm + (size_t)r * Hz + k0 + c8 * 8);
            }
            __syncthreads();
            short8v a = *(const short8v*)(As + (wave * 16 + l15) * 40 + g * 8);
            #pragma unroll
            for (int n = 0; n < 4; ++n) {
                short8v bn = *(const short8v*)(Bs + (n * 16 + l15) * 40 + g * 8);
                acc[n] = __builtin_amdgcn_mfma_f32_16x16x32_bf16(a, bn, acc[n], 0, 0, 0);
            }
        }
    }

    #pragma unroll
    for (int rr = 0; rr < 4; ++rr) {
        int row = row0 + wave * 16 + g * 4 + rr;
        #pragma unroll
        for (int n = 0; n < 4; ++n) {
            int col = n * 16 + l15;
            C[(size_t)row * Fz + col] = acc[n][rr] + bias[col];
        }
    }
}

// ===========================================================================
// Kernels
// ===========================================================================

__device__ inline void transpose_tile2(const float* __restrict__ in,
                                       unsigned short* __restrict__ out,
                                       int R, int C, int bx, int by, int tid)
{
    __shared__ float t[32][33];
    const int c0 = bx * 32, r0 = by * 32;
    const int lc = tid & 31, lr8 = tid >> 5;
    #pragma unroll
    for (int i = 0; i < 4; ++i) {
        int r = lr8 + i * 8;
        t[r][lc] = in[(size_t)(r0 + r) * C + c0 + lc];
    }
    __syncthreads();
    #pragma unroll
    for (int i = 0; i < 4; ++i) {
        int oc = lr8 + i * 8;
        out[(size_t)(c0 + oc) * R + r0 + lc] = f2bf_rne(t[lc][oc]);
    }
}

__global__ __launch_bounds__(256) void prep_kernel(
    const float* __restrict__ W_num, const float* __restrict__ W_ad,
    const float* __restrict__ Wq, const float* __restrict__ Wk,
    const float* __restrict__ Wv, const float* __restrict__ Wo,
    const float* __restrict__ W_out, const float* __restrict__ bo,
    const float* __restrict__ b_out, const float* __restrict__ b_ad,
    const float* __restrict__ bk, const float* __restrict__ bv,
    const int* __restrict__ present,
    unsigned short* __restrict__ WnumT, unsigned short* __restrict__ WadT,
    unsigned short* __restrict__ WqT, unsigned short* __restrict__ WkT,
    unsigned short* __restrict__ WvT, unsigned short* __restrict__ WoT,
    unsigned short* __restrict__ WoutT, float* __restrict__ bocomb,
    float* __restrict__ bkv, unsigned short* __restrict__ WadB,
    unsigned int* __restrict__ plist)
{
    const int bid = blockIdx.x;
    const int tid = threadIdx.x;
    if (bid < 16) {
        transpose_tile2(W_num, WnumT, Fz, Hz, bid & 7, bid >> 3, tid);
    } else if (bid < 208) {
        int lid = bid - 16;
        transpose_tile2(W_ad, WadT, Dz, Hz, lid & 7, lid >> 3, tid);
    } else if (bid < 464) {
        int lid = bid - 208;
        int which = lid >> 6, t8 = lid & 63;
        const float* in = which == 0 ? Wq : which == 1 ? Wk : which == 2 ? Wv : Wo;
        unsigned short* out = which == 0 ? WqT : which == 1 ? WkT : which == 2 ? WvT : WoT;
        transpose_tile2(in, out, Hz, Hz, t8 & 7, t8 >> 3, tid);
    } else if (bid < 480) {
        int lid = bid - 464;
        transpose_tile2(W_out, WoutT, Hz, Fz, lid & 1, lid >> 1, tid);
    } else if (bid == 480) {              // pairlist
        __shared__ int cnt[64];
        __shared__ int off[64];
        int i = tid;
        if (i < 64) {
            int c = 0;
            for (int j = i + 1; j < 64; ++j)
                if (present[i * 64 + j] != 0) c++;
            cnt[i] = c;
        }
        __syncthreads();
        if (i == 0) {
            int t = 0;
            for (int r = 0; r < 64; ++r) { off[r] = t; t += cnt[r]; }
            plist[0] = (unsigned)t;
        }
        __syncthreads();
        if (i < 64) {
            int o = 1 + off[i];
            for (int j = i + 1; j < 64; ++j)
                if (present[i * 64 + j] != 0) plist[o++] = (unsigned)(i * 64 + j);
        }
    } else if (bid == 481) {              // bocomb
        int c = tid;
        if (c < 64) {
            float a = b_out[c];
            for (int j = 0; j < 256; ++j) a = fmaf(bo[j], W_out[(size_t)j * 64 + c], a);
            bocomb[c] = a;
        }
    } else if (bid < 484) {               // bkv
        int c = tid;
        const float* Wx = (bid == 482) ? Wk : Wv;
        const float* bx = (bid == 482) ? bk : bv;
        float a = bx[c];
        for (int j = 0; j < 256; ++j) a = fmaf(b_ad[j], Wx[(size_t)j * Hz + c], a);
        bkv[(bid - 482) * 256 + c] = a;
    } else {                              // WadB bf16 copy
        int lid = bid - 484;
        int base = lid * 1024 + tid * 4;
        #pragma unroll
        for (int j = 0; j < 4; ++j) WadB[base + j] = f2bf_rne(W_ad[base + j]);
    }
}

// combo1: WoWoutT(2) | WadkvT(24) | pooled2(4) | mask(2048) | pe(1024)
__global__ __launch_bounds__(256) void combo1_kernel(
    const unsigned short* __restrict__ WoutT, const unsigned short* __restrict__ WoT,
    unsigned short* __restrict__ WoWoutT,
    const unsigned short* __restrict__ WkT, const unsigned short* __restrict__ WadB,
    unsigned short* __restrict__ WadkvT,
    const float* __restrict__ sapE, const float* __restrict__ W_sap,
    const float* __restrict__ b_sap, float* __restrict__ pooled,
    const float* __restrict__ batch_data, const float* __restrict__ mask_probs,
    unsigned short* __restrict__ safe_bf, float* __restrict__ stoch_out,
    unsigned long long* __restrict__ mask64,
    const float* __restrict__ pair_emb, const unsigned int* __restrict__ plist,
    unsigned short* __restrict__ Pe)
{
    __shared__ unsigned short smem[10240];   // 20 KB
    const int bid = blockIdx.x;
    const int tid = threadIdx.x;
    if (bid < 2) {
        gemm2_body<64, 128, true, 3>(smem, WoutT, WoT, nullptr, nullptr,
                                     WoWoutT, 64, Hz, Hz, bid, 0, tid);
    } else if (bid < 26) {
        int lid = bid - 2;
        gemm2_body<128, 128, true, 3>(smem, WkT, WadB, nullptr, nullptr,
                                      WadkvT, 512, Dz, Hz, lid % 6, lid / 6, tid);
    } else if (bid < 30) {
        pooled_body(smem, sapE, W_sap, b_sap, pooled, bid - 26, tid);
    } else if (bid < 2078) {
        mask_body(batch_data, mask_probs, safe_bf, stoch_out, mask64, bid - 30, tid);
    } else {
        pe_body(pair_emb, plist, Pe, bid - 2078, tid);
    }
}

// combo2: queryGEMM(128) | wbuild(512) | PeWaT GEMM(32)
__global__ __launch_bounds__(256) void combo2_kernel(
    const unsigned short* __restrict__ safe_bf, const unsigned short* __restrict__ WnumT,
    const float* __restrict__ b_num, const float* __restrict__ pooled,
    unsigned short* __restrict__ qBF,
    const unsigned long long* __restrict__ mask64, const unsigned int* __restrict__ plist,
    unsigned long long* __restrict__ sel, float* __restrict__ inv_cnt,
    const unsigned short* __restrict__ WadkvT, const unsigned short* __restrict__ Pe,
    unsigned short* __restrict__ PeWaT)
{
    __shared__ unsigned short smem[10240];
    const int bid = blockIdx.x;
    const int tid = threadIdx.x;
    if (bid < 128) {
        gemm2_body<128, 128, true, 1>(smem, safe_bf, WnumT, b_num, pooled,
                                      qBF, BTz, Hz, Fz, bid & 1, bid >> 1, tid);
    } else if (bid < 640) {
        wbuild_body(smem, mask64, plist, sel, inv_cnt, bid - 128, tid);
    } else {
        int lid = bid - 640;   // 32 blocks: M=512 (by 0..3), N=1024 (bx 0..7)
        gemm2_body<128, 128, true, 3>(smem, WadkvT, Pe, nullptr, nullptr,
                                      PeWaT, 512, NPAIRPAD, Dz, lid & 7, lid >> 3, tid);
    }
}

// combo3: selkv register GEMM(512) | qproj register GEMM(256). NO LDS.
__global__ __launch_bounds__(256) void combo3_kernel(
    const unsigned long long* __restrict__ sel, const unsigned short* __restrict__ PeWaT,
    const float* __restrict__ inv_cnt, const float* __restrict__ bkv,
    unsigned short* __restrict__ kvproj,
    const unsigned short* __restrict__ qBF, const unsigned short* __restrict__ WqT,
    const float* __restrict__ bq, unsigned short* __restrict__ qbb)
{
    const int bid = blockIdx.x;
    const int tid = threadIdx.x;
    if (bid < 512) {
        gemm_selkv_reg_body(sel, PeWaT, inv_cnt, bkv, kvproj,
                            bid & 3, bid >> 2, tid);
    } else {
        int lid = bid - 512;   // 256 blocks: BM=64 (by 0..127), BN=128 (bx 0..1)
        gemm_reg_body(qBF, WqT, bq, qbb, Hz, Hz, lid & 1, lid >> 1, tid);
    }
}

// Fused attention: QK^T -> softmax -> PV (PV in 64-key chunks).
__global__ __launch_bounds__(256) void attn_fused_kernel(
    const unsigned short* __restrict__ q, const unsigned short* __restrict__ kp,
    unsigned short* __restrict__ probs, unsigned short* __restrict__ pv)
{
    int blk = blockIdx.x;
    int bh = blk >> 1, half = blk & 1;
    int b = bh >> 2, h = bh & 3;
    __shared__ unsigned short smem[128 * QKPAD + 256 * QKPAD];
    unsigned short* Ql = smem;
    unsigned short* Kl = smem + 128 * QKPAD;
    const int tid = threadIdx.x;

    const unsigned short* qbase = q + (size_t)(b * Tz + half * 128) * Hz + h * HDz;
    #pragma unroll
    for (int i = 0; i < 4; ++i) {
        int e = tid + i * 256;
        int r = e >> 3, c8 = e & 7;
        *(ushort8v*)&Ql[r * QKPAD + c8 * 8] =
            *(const ushort8v*)(qbase + (size_t)r * Hz + c8 * 8);
    }
    const unsigned short* kbase = kp + (size_t)(b * Tz) * 512 + h * HDz;
    #pragma unroll
    for (int i = 0; i < 8; ++i) {
        int e = tid + i * 256;
        int r = e >> 3, c8 = e & 7;
        *(ushort8v*)&Kl[r * QKPAD + c8 * 8] =
            *(const ushort8v*)(kbase + (size_t)r * 512 + c8 * 8);
    }
    __syncthreads();

    const int lane = tid & 63, wave = tid >> 6;
    const int l15 = lane & 15, g = lane >> 4;

    f32x4 acc[2][16] = {};
    #pragma unroll
    for (int ks = 0; ks < 2; ++ks) {
        short8v a0 = *(const short8v*)&Ql[(wave * 32 + l15) * QKPAD + ks * 32 + g * 8];
        short8v a1 = *(const short8v*)&Ql[(wave * 32 + 16 + l15) * QKPAD + ks * 32 + g * 8];
        #pragma unroll
        for (int n = 0; n < 16; ++n) {
            short8v bn = *(const short8v*)&Kl[(n * 16 + l15) * QKPAD + ks * 32 + g * 8];
            acc[0][n] = __builtin_amdgcn_mfma_f32_16x16x32_bf16(a0, bn, acc[0][n], 0, 0, 0);
            acc[1][n] = __builtin_amdgcn_mfma_f32_16x16x32_bf16(a1, bn, acc[1][n], 0, 0, 0);
        }
    }

    #pragma unroll
    for (int m = 0; m < 2; ++m) {
        #pragma unroll
        for (int rr = 0; rr < 4; ++rr) {
            float mx = -1e30f;
            #pragma unroll
            for (int n = 0; n < 16; ++n) mx = fmaxf(mx, acc[m][n][rr]);
            #pragma unroll
            for (int s = 1; s < 16; s <<= 1) mx = fmaxf(mx, __shfl_xor(mx, s));
            float sum = 0.0f;
            #pragma unroll
            for (int n = 0; n < 16; ++n) {
                float e = __expf(0.125f * (acc[m][n][rr] - mx));
                acc[m][n][rr] = e;
                sum += e;
            }
            #pragma unroll
            for (int s = 1; s < 16; s <<= 1) sum += __shfl_xor(sum, s);
            float inv = 1.0f / sum;
            int row = half * 128 + wave * 32 + m * 16 + g * 4 + rr;
            unsigned short* dst = probs + ((size_t)bh * Tz + row) * Tz;
            #pragma unroll
            for (int n = 0; n < 16; ++n) {
                float p = acc[m][n][rr] * inv;
                acc[m][n][rr] = p;
                dst[n * 16 + l15] = f2bf_rne(p);
            }
        }
    }
    __syncthreads();

    unsigned short* Vt = smem;                 // [64][VTPAD]
    unsigned short* Pl = smem + 64 * VTPAD;    // [128][PLPAD=72]
    const unsigned short* vbase = kp + (size_t)(b * Tz) * 512 + 256 + h * HDz;
    #pragma unroll
    for (int i = 0; i < 8; ++i) {
        int e = tid + i * 256;
        int key = e >> 3, c8 = e & 7;
        ushort8v v8 = *(const ushort8v*)(vbase + (size_t)key * 512 + c8 * 8);
        #pragma unroll
        for (int j = 0; j < 8; ++j)
            Vt[(c8 * 8 + j) * VTPAD + key] = v8[j];
    }

    f32x4 accpv[2][4] = {};
    for (int ks = 0; ks < 4; ++ks) {          // 64-key chunks
        #pragma unroll
        for (int m = 0; m < 2; ++m) {
            #pragma unroll
            for (int rr = 0; rr < 4; ++rr) {
                int row = wave * 32 + m * 16 + g * 4 + rr;
                #pragma unroll
                for (int j = 0; j < 4; ++j)
                    Pl[row * PLPAD + j * 16 + l15] = f2bf_rne(acc[m][4 * ks + j][rr]);
            }
        }
        __syncthreads();   // Vt ready (1st iter) + Pl ready
        #pragma unroll
        for (int kk = 0; kk < 2; ++kk) {
            short8v a0 = *(const short8v*)&Pl[(wave * 32 + l15) * PLPAD + kk * 32 + g * 8];
            short8v a1 = *(const short8v*)&Pl[(wave * 32 + 16 + l15) * PLPAD + kk * 32 + g * 8];
            #pragma unroll
            for (int n = 0; n < 4; ++n) {
                short8v bn = *(const short8v*)&Vt[(n * 16 + l15) * VTPAD + ks * 64 + kk * 32 + g * 8];
                accpv[0][n] = __builtin_amdgcn_mfma_f32_16x16x32_bf16(a0, bn, accpv[0][n], 0, 0, 0);
                accpv[1][n] = __builtin_amdgcn_mfma_f32_16x16x32_bf16(a1, bn, accpv[1][n], 0, 0, 0);
            }
        }
        __syncthreads();
    }

    #pragma unroll
    for (int m = 0; m < 2; ++m) {
        #pragma unroll
        for (int rr = 0; rr < 4; ++rr) {
            int row = b * Tz + half * 128 + wave * 32 + m * 16 + g * 4 + rr;
            #pragma unroll
            for (int n = 0; n < 4; ++n)
                pv[(size_t)row * Hz + h * HDz + n * 16 + l15] = f2bf_rne(accpv[m][n][rr]);
        }
    }
}

// combo4: meanheads(1024) | final(128)
__global__ __launch_bounds__(256) void combo4_kernel(
    const unsigned short* __restrict__ probs, float* __restrict__ out_attn,
    const unsigned short* __restrict__ qBF, const unsigned short* __restrict__ pvb,
    const unsigned short* __restrict__ WoutT, const unsigned short* __restrict__ WoWoutT,
    const float* __restrict__ bocomb, float* __restrict__ out_imputed)
{
    __shared__ unsigned short smem[5120];
    const int bid = blockIdx.x;
    const int tid = threadIdx.x;
    if (bid < 1024) {
        meanheads_body(probs, out_attn, bid, tid);
    } else {
        final_body(smem, qBF, pvb, WoutT, WoWoutT, bocomb, out_imputed, bid - 1024, tid);
    }
}

// ---------------------------------------------------------------------------
extern "C" void kernel_launch(void* const* d_in, const int* in_sizes, int n_in,
                              void* d_out, int out_size, void* d_ws, size_t ws_size,
                              hipStream_t stream)
{
    const float* batch_data = (const float*)d_in[0];
    const float* mask_probs = (const float*)d_in[1];
    const float* sapE       = (const float*)d_in[2];
    const float* pair_emb   = (const float*)d_in[3];
    const int*   pair_present = (const int*)d_in[4];
    const float* W_num = (const float*)d_in[5];  const float* b_num = (const float*)d_in[6];
    const float* W_sap = (const float*)d_in[7];  const float* b_sap = (const float*)d_in[8];
    const float* W_ad  = (const float*)d_in[9];  const float* b_ad  = (const float*)d_in[10];
    const float* Wq = (const float*)d_in[11]; const float* bq = (const float*)d_in[12];
    const float* Wk = (const float*)d_in[13]; const float* bk = (const float*)d_in[14];
    const float* Wv = (const float*)d_in[15]; const float* bv = (const float*)d_in[16];
    const float* Wo = (const float*)d_in[17]; const float* bo = (const float*)d_in[18];
    const float* W_out = (const float*)d_in[19]; const float* b_out = (const float*)d_in[20];

    float* out = (float*)d_out;
    float* out_imputed = out;                 // [B,T,F]
    float* out_stoch   = out + 524288;        // [B,T,F]
    float* out_attn    = out + 1048576;       // [B,T,T]

    float* ws = (float*)d_ws;
    unsigned short* safe_bf = (unsigned short*)ws;             // bf16 [8192][64]
    unsigned short* qBF   = (unsigned short*)(ws + 524288);    // bf16 [8192][256]
    unsigned short* probs = (unsigned short*)(ws + 2621440);   // bf16 [128][256][256]
    unsigned long long* sel = (unsigned long long*)(ws + 9961472); // u64 [8192][16]
    unsigned short* qbb   = (unsigned short*)(ws + 11010048);  // bf16 [8192][256]
    unsigned short* Pe    = (unsigned short*)(ws + 15204352);  // bf16 [1024][768] (dead after combo2)
    unsigned short* kvproj = (unsigned short*)(ws + 15204352); // bf16 [8192][512] (over dead Pe)
    unsigned short* pvb   = (unsigned short*)(ws + 17301504);  // bf16 [8192][256]
    unsigned short* WoWoutT = (unsigned short*)(ws + 18350080);// bf16 [64][256]
    float* bocomb = ws + 18358272;                             // 64 f32
    float* bkv    = ws + 18358336;                             // 512 f32
    float* inv_cnt = ws + 18358848;                            // 8192 f32
    unsigned short* WadkvT = (unsigned short*)(ws + 18367040); // bf16 [512][768]
    unsigned short* WadB   = (unsigned short*)(ws + 18563648); // bf16 [768][256]
    unsigned short* PeWaT  = (unsigned short*)(ws + 18661952); // bf16 [512][1024]
    float* pooled = ws + 19398656;
    unsigned long long* mask64 = (unsigned long long*)(ws + 19398912);
    unsigned int* plist = (unsigned int*)(ws + 19415296);

    unsigned short* wT = (unsigned short*)(ws + 19419392);
    unsigned short* WnumT = wT;                  // [256][64]
    unsigned short* WadT  = wT + 16384;          // [256][768]
    unsigned short* WqT   = wT + 212992;         // [256][256]
    unsigned short* WkT   = wT + 278528;         // (WkT,WvT contiguous)
    unsigned short* WvT   = wT + 344064;
    unsigned short* WoT   = wT + 409600;
    unsigned short* WoutT = wT + 475136;         // [64][256]

    // 1. prep
    prep_kernel<<<676, 256, 0, stream>>>(
        W_num, W_ad, Wq, Wk, Wv, Wo, W_out, bo, b_out, b_ad, bk, bv, pair_present,
        WnumT, WadT, WqT, WkT, WvT, WoT, WoutT, bocomb, bkv, WadB, plist);
    // 2. combo1: WoWoutT | WadkvT | pooled | mask | Pe gather
    combo1_kernel<<<3102, 256, 0, stream>>>(
        WoutT, WoT, WoWoutT, WkT, WadB, WadkvT,
        sapE, W_sap, b_sap, pooled,
        batch_data, mask_probs, safe_bf, out_stoch, mask64,
        pair_emb, plist, Pe);
    // 3. combo2: query GEMM | wbuild | PeWaT = WadkvT @ Pe^T
    combo2_kernel<<<672, 256, 0, stream>>>(
        safe_bf, WnumT, b_num, pooled, qBF,
        mask64, plist, sel, inv_cnt, WadkvT, Pe, PeWaT);
    // 4. combo3: selkv reg-GEMM | q projection reg-GEMM (no LDS, no barriers)
    combo3_kernel<<<768, 256, 0, stream>>>(
        sel, PeWaT, inv_cnt, bkv, kvproj, qBF, WqT, bq, qbb);
    // 5. fused attention
    attn_fused_kernel<<<256, 256, 0, stream>>>(qbb, kvproj, probs, pvb);
    // 6. combo4: meanheads | final
    combo4_kernel<<<1152, 256, 0, stream>>>(
        probs, out_attn, qBF, pvb, WoutT, WoWoutT, bocomb, out_imputed);
}

// Round 13
// 124.435 us; speedup vs baseline: 1.2157x; 1.2157x over previous
//
#include <hip/hip_runtime.h>
#include <hip/hip_bf16.h>

// Shapes
#define Bz 32
#define Tz 256
#define Fz 64
#define Dz 768
#define Sz 768
#define Hz 256
#define NHz 4
#define HDz 64
#define BTz 8192  // B*T
#define NPAIRPAD 1024
#define QKPAD 72   // bf16 units; 144B row stride: 2-way bank alias (free)
#define VTPAD 264
#define PLPAD 72   // PV 64-key chunk

typedef __attribute__((ext_vector_type(8))) short short8v;
typedef __attribute__((ext_vector_type(8))) unsigned short ushort8v;
typedef __attribute__((ext_vector_type(4))) float f32x4;

__device__ inline unsigned short f2bf_rne(float x) {
    unsigned u = __float_as_uint(x);
    unsigned r = (u + 0x7fffu + ((u >> 16) & 1u)) >> 16;
    return (unsigned short)r;
}
__device__ inline float bf2f(unsigned short x) {
    return __uint_as_float(((unsigned)x) << 16);
}
__device__ inline short8v expand8(unsigned bits) {
    short8v r;
    #pragma unroll
    for (int j = 0; j < 8; ++j)
        r[j] = (bits & (1u << j)) ? (short)0x3f80 : (short)0;
    return r;
}

// ===========================================================================
// Device bodies
// ===========================================================================

// Unified LDS-staged MFMA GEMM body.
template <int BM, int BN, bool OUTBF16, int B2MODE>
__device__ __forceinline__ void gemm2_body(
    unsigned short* __restrict__ smem,
    const unsigned short* __restrict__ A,
    const unsigned short* __restrict__ Bt,
    const float* __restrict__ bias, const float* __restrict__ bias2,
    void* __restrict__ Cv, int M, int N, int K, int bx, int by, int tid)
{
    constexpr int WC = BN / 64;
    constexpr int WR = 4 / WC;
    constexpr int RW = BM / WR;
    constexpr int MT = RW / 16;
    constexpr int NT = 4;
    unsigned short* As = smem;
    unsigned short* Bs = smem + BM * 40;
    const int lane = tid & 63, wave = tid >> 6;
    const int l15 = lane & 15, g = lane >> 4;
    const int wr = wave / WC, wc = wave % WC;
    const int row0 = by * BM, col0 = bx * BN;

    f32x4 acc[MT][NT] = {};

    for (int k0 = 0; k0 < K; k0 += 32) {
        __syncthreads();
        #pragma unroll
        for (int i = 0; i < BM * 4 / 256; ++i) {
            int e = tid + i * 256;
            int r = e >> 2, c8 = e & 3;
            *(ushort8v*)(As + r * 40 + c8 * 8) =
                *(const ushort8v*)(A + (size_t)(row0 + r) * K + k0 + c8 * 8);
        }
        #pragma unroll
        for (int i = 0; i < BN * 4 / 256; ++i) {
            int e = tid + i * 256;
            int n = e >> 2, c = e & 3;
            *(ushort8v*)(Bs + n * 40 + c * 8) =
                *(const ushort8v*)(Bt + (size_t)(col0 + n) * K + k0 + c * 8);
        }
        __syncthreads();

        short8v a[MT], b[NT];
        #pragma unroll
        for (int m = 0; m < MT; ++m)
            a[m] = *(const short8v*)(As + (wr * RW + m * 16 + l15) * 40 + g * 8);
        #pragma unroll
        for (int n = 0; n < NT; ++n)
            b[n] = *(const short8v*)(Bs + (wc * 64 + n * 16 + l15) * 40 + g * 8);
        #pragma unroll
        for (int m = 0; m < MT; ++m)
            #pragma unroll
            for (int n = 0; n < NT; ++n)
                acc[m][n] = __builtin_amdgcn_mfma_f32_16x16x32_bf16(a[m], b[n], acc[m][n], 0, 0, 0);
    }

    #pragma unroll
    for (int m = 0; m < MT; ++m) {
        #pragma unroll
        for (int rr = 0; rr < 4; ++rr) {
            int row = row0 + wr * RW + m * 16 + g * 4 + rr;
            #pragma unroll
            for (int n = 0; n < NT; ++n) {
                int col = col0 + wc * 64 + n * 16 + l15;
                float o = acc[m][n][rr];
                if (B2MODE == 2) {
                    o += (col < (N >> 1)) ? bias[col] : bias2[col - (N >> 1)];
                } else if (B2MODE != 3) {
                    o += bias[col];
                    if (B2MODE == 1) o += bias2[col];
                }
                if (OUTBF16) ((unsigned short*)Cv)[(size_t)row * N + col] = f2bf_rne(o);
                else         ((float*)Cv)[(size_t)row * N + col] = o;
            }
        }
    }
}

// selkv hybrid GEMM: kvproj = inv_cnt ⊙ (Sel-bits @ PeWaT^T) + bkv.
// BM=64, BN=128, K=1024. A expanded from sel bits IN REGISTERS (no LDS);
// B staged in LDS in 128-k chunks, XOR-swizzled (16B slot ^= row&7).
// Barriers: 2 per 128-k chunk = 16 total (vs 64 in the per-32-k version).
__device__ __forceinline__ void gemm_selkv_body2(
    unsigned short* __restrict__ smem,         // >= 128*128 ushorts (32 KB)
    const unsigned long long* __restrict__ sel,
    const unsigned short* __restrict__ Bt,     // PeWaT [512][1024]
    const float* __restrict__ rs,              // inv_cnt [8192]
    const float* __restrict__ bias,            // bkv [512]
    unsigned short* __restrict__ C,            // kvproj [8192][512]
    int bx, int by, int tid)
{
    unsigned short* Bs = smem;                 // [128 rows][128 k], swizzled
    const int lane = tid & 63, wave = tid >> 6;
    const int l15 = lane & 15, g = lane >> 4;
    const int wr = wave >> 1, wc = wave & 1;
    const int row0 = by * 64, col0 = bx * 128;

    const unsigned long long* selr0 = sel + (size_t)(row0 + wr * 32 + l15) * 16;
    const unsigned long long* selr1 = selr0 + 16 * 16;   // +16 rows

    f32x4 acc[2][4] = {};

    for (int kc = 0; kc < 1024; kc += 128) {
        __syncthreads();
        #pragma unroll
        for (int i = 0; i < 8; ++i) {            // 128 rows x 16 slots of 8
            int e = tid + i * 256;
            int r = e >> 4, c8 = e & 15;
            int slot = c8 ^ (r & 7);
            *(ushort8v*)(Bs + r * 128 + slot * 8) =
                *(const ushort8v*)(Bt + (size_t)(col0 + r) * 1024 + kc + c8 * 8);
        }
        __syncthreads();

        #pragma unroll
        for (int kk = 0; kk < 4; ++kk) {
            const int k0 = kc + kk * 32;
            const int word = k0 >> 6;
            const int shift = (k0 & 32) + g * 8;
            short8v a0 = expand8((unsigned)(selr0[word] >> shift) & 0xFFu);
            short8v a1 = expand8((unsigned)(selr1[word] >> shift) & 0xFFu);
            #pragma unroll
            for (int n = 0; n < 4; ++n) {
                int row = wc * 64 + n * 16 + l15;
                int slot = (kk * 4 + g) ^ (row & 7);
                short8v bn = *(const short8v*)(Bs + row * 128 + slot * 8);
                acc[0][n] = __builtin_amdgcn_mfma_f32_16x16x32_bf16(a0, bn, acc[0][n], 0, 0, 0);
                acc[1][n] = __builtin_amdgcn_mfma_f32_16x16x32_bf16(a1, bn, acc[1][n], 0, 0, 0);
            }
        }
    }

    #pragma unroll
    for (int m = 0; m < 2; ++m) {
        #pragma unroll
        for (int rr = 0; rr < 4; ++rr) {
            int row = row0 + wr * 32 + m * 16 + g * 4 + rr;
            float s = rs[row];
            #pragma unroll
            for (int n = 0; n < 4; ++n) {
                int col = col0 + wc * 64 + n * 16 + l15;
                C[(size_t)row * 512 + col] = f2bf_rne(acc[m][n][rr] * s + bias[col]);
            }
        }
    }
}

// masking body
__device__ __forceinline__ void mask_body(
    const float* __restrict__ bd, const float* __restrict__ mp,
    unsigned short* __restrict__ safe_bf, float* __restrict__ stoch_out,
    unsigned long long* __restrict__ mask64, int bid, int tid)
{
    int idx = bid * 256 + tid;
    float x = bd[idx];
    float p = mp[idx];
    unsigned xb = __float_as_uint(x);
    bool valid = ((xb & 0x7fffffffu) <= 0x7f800000u);
    bool st = (p < 0.3f) && valid;
    bool sv = valid && !st;
    safe_bf[idx] = sv ? f2bf_rne(x) : 0;
    stoch_out[idx] = st ? 1.0f : 0.0f;
    unsigned long long m = __ballot(sv);
    if ((tid & 63) == 0) mask64[idx >> 6] = m;
}

// pooled body
__device__ __forceinline__ void pooled_body(
    unsigned short* __restrict__ smem,
    const float* __restrict__ E, const float* __restrict__ W_sap,
    const float* __restrict__ b_sap, float* __restrict__ pooled, int bid, int tid)
{
    float* colmean = (float*)smem;
    float* red = colmean + Sz;
    for (int s = tid; s < Sz; s += 256) {
        float a = 0.0f;
        #pragma unroll 8
        for (int f = 0; f < Fz; ++f) a += E[(size_t)f * Sz + s];
        colmean[s] = a * (1.0f / 64.0f);
    }
    __syncthreads();
    const int hl = tid & 63, sg = tid >> 6;
    const int h = bid * 64 + hl;
    float acc = 0.0f;
    #pragma unroll 4
    for (int s = sg; s < Sz; s += 4)
        acc = fmaf(colmean[s], W_sap[(size_t)s * Hz + h], acc);
    red[sg * 64 + hl] = acc;
    __syncthreads();
    if (sg == 0)
        pooled[h] = b_sap[h] + ((red[hl] + red[64 + hl]) + (red[128 + hl] + red[192 + hl]));
}

// wbuild body
__device__ __forceinline__ void wbuild_body(
    unsigned short* __restrict__ smem,
    const unsigned long long* __restrict__ mask64,
    const unsigned int* __restrict__ plist,
    unsigned long long* __restrict__ sel, float* __restrict__ inv_cnt,
    int bid, int tid)
{
    unsigned int* pl = (unsigned int*)smem;
    for (int i = tid; i < NPAIRPAD; i += 256) pl[i] = plist[1 + i];
    __syncthreads();
    const int np = (int)plist[0];
    const int btl = tid >> 4, w = tid & 15;
    const int bt = bid * 16 + btl;
    unsigned long long m = mask64[bt];
    unsigned long long word = 0ull;
    int pbase = w * 64;
    int jmax = min(64, np - pbase);
    for (int j = 0; j < jmax; ++j) {
        unsigned ij = pl[pbase + j];
        unsigned long long bit = (m >> (ij >> 6)) & (m >> (ij & 63)) & 1ull;
        word |= bit << j;
    }
    sel[(size_t)bt * 16 + w] = word;
    int c = __popcll(word);
    #pragma unroll
    for (int s = 1; s < 16; s <<= 1) c += __shfl_xor(c, s);
    if (w == 0) inv_cnt[bt] = c > 0 ? 1.0f / (float)c : 0.0f;
}

// pe body
__device__ __forceinline__ void pe_body(
    const float* __restrict__ pair_emb, const unsigned int* __restrict__ plist,
    unsigned short* __restrict__ Pe, int p, int t)
{
    int np = (int)plist[0];
    if (p < np) {
        unsigned ij = plist[1 + p];
        const float* src = pair_emb + (size_t)ij * Dz;
        #pragma unroll
        for (int c = 0; c < 3; ++c)
            Pe[(size_t)p * Dz + t + c * 256] = f2bf_rne(src[t + c * 256]);
    } else {
        #pragma unroll
        for (int c = 0; c < 3; ++c)
            Pe[(size_t)p * Dz + t + c * 256] = 0;
    }
}

// meanheads body
__device__ __forceinline__ void meanheads_body(
    const unsigned short* __restrict__ probs, float* __restrict__ out3,
    int bid, int tid)
{
    int idx = bid * 256 + tid;
    int tk8 = idx & 31;
    int btq = idx >> 5;
    int b = btq >> 8, tq = btq & 255;
    float acc[8] = {};
    #pragma unroll
    for (int h = 0; h < 4; ++h) {
        int bh = b * 4 + h;
        ushort8v p = *(const ushort8v*)&probs[(((size_t)bh * Tz + tq) << 8) + tk8 * 8];
        #pragma unroll
        for (int j = 0; j < 8; ++j) acc[j] += bf2f(p[j]) * 0.25f;
    }
    float* dst = out3 + ((size_t)btq << 8) + tk8 * 8;
    float4 o0 = {acc[0], acc[1], acc[2], acc[3]};
    float4 o1 = {acc[4], acc[5], acc[6], acc[7]};
    *(float4*)dst = o0;
    *(float4*)(dst + 4) = o1;
}

// final body
__device__ __forceinline__ void final_body(
    unsigned short* __restrict__ smem,
    const unsigned short* __restrict__ qBF, const unsigned short* __restrict__ pvb,
    const unsigned short* __restrict__ WoutT, const unsigned short* __restrict__ WWT,
    const float* __restrict__ bias, float* __restrict__ C, int bid, int tid)
{
    unsigned short* As = smem;
    unsigned short* Bs = smem + 64 * 40;
    const int lane = tid & 63, wave = tid >> 6;
    const int l15 = lane & 15, g = lane >> 4;
    const int row0 = bid * 64;

    f32x4 acc[4] = {};

    for (int ph = 0; ph < 2; ++ph) {
        const unsigned short* Am = ph == 0 ? qBF : pvb;
        const unsigned short* Bm = ph == 0 ? WoutT : WWT;
        for (int k0 = 0; k0 < 256; k0 += 32) {
            __syncthreads();
            {
                int r = tid >> 2, c8 = tid & 3;
                *(ushort8v*)(As + r * 40 + c8 * 8) =
                    *(const ushort8v*)(Am + (size_t)(row0 + r) * Hz + k0 + c8 * 8);
                *(ushort8v*)(Bs + r * 40 + c8 * 8) =
                    *(const ushort8v*)(Bm + (size_t)r * Hz + k0 + c8 * 8);
            }
            __syncthreads();
            short8v a = *(const short8v*)(As + (wave * 16 + l15) * 40 + g * 8);
            #pragma unroll
            for (int n = 0; n < 4; ++n) {
                short8v bn = *(const short8v*)(Bs + (n * 16 + l15) * 40 + g * 8);
                acc[n] = __builtin_amdgcn_mfma_f32_16x16x32_bf16(a, bn, acc[n], 0, 0, 0);
            }
        }
    }

    #pragma unroll
    for (int rr = 0; rr < 4; ++rr) {
        int row = row0 + wave * 16 + g * 4 + rr;
        #pragma unroll
        for (int n = 0; n < 4; ++n) {
            int col = n * 16 + l15;
            C[(size_t)row * Fz + col] = acc[n][rr] + bias[col];
        }
    }
}

// ===========================================================================
// Kernels
// ===========================================================================

__device__ inline void transpose_tile2(const float* __restrict__ in,
                                       unsigned short* __restrict__ out,
                                       int R, int C, int bx, int by, int tid)
{
    __shared__ float t[32][33];
    const int c0 = bx * 32, r0 = by * 32;
    const int lc = tid & 31, lr8 = tid >> 5;
    #pragma unroll
    for (int i = 0; i < 4; ++i) {
        int r = lr8 + i * 8;
        t[r][lc] = in[(size_t)(r0 + r) * C + c0 + lc];
    }
    __syncthreads();
    #pragma unroll
    for (int i = 0; i < 4; ++i) {
        int oc = lr8 + i * 8;
        out[(size_t)(c0 + oc) * R + r0 + lc] = f2bf_rne(t[lc][oc]);
    }
}

__global__ __launch_bounds__(256) void prep_kernel(
    const float* __restrict__ W_num, const float* __restrict__ W_ad,
    const float* __restrict__ Wq, const float* __restrict__ Wk,
    const float* __restrict__ Wv, const float* __restrict__ Wo,
    const float* __restrict__ W_out, const float* __restrict__ bo,
    const float* __restrict__ b_out, const float* __restrict__ b_ad,
    const float* __restrict__ bk, const float* __restrict__ bv,
    const int* __restrict__ present,
    unsigned short* __restrict__ WnumT, unsigned short* __restrict__ WadT,
    unsigned short* __restrict__ WqT, unsigned short* __restrict__ WkT,
    unsigned short* __restrict__ WvT, unsigned short* __restrict__ WoT,
    unsigned short* __restrict__ WoutT, float* __restrict__ bocomb,
    float* __restrict__ bkv, unsigned short* __restrict__ WadB,
    unsigned int* __restrict__ plist)
{
    const int bid = blockIdx.x;
    const int tid = threadIdx.x;
    if (bid < 16) {
        transpose_tile2(W_num, WnumT, Fz, Hz, bid & 7, bid >> 3, tid);
    } else if (bid < 208) {
        int lid = bid - 16;
        transpose_tile2(W_ad, WadT, Dz, Hz, lid & 7, lid >> 3, tid);
    } else if (bid < 464) {
        int lid = bid - 208;
        int which = lid >> 6, t8 = lid & 63;
        const float* in = which == 0 ? Wq : which == 1 ? Wk : which == 2 ? Wv : Wo;
        unsigned short* out = which == 0 ? WqT : which == 1 ? WkT : which == 2 ? WvT : WoT;
        transpose_tile2(in, out, Hz, Hz, t8 & 7, t8 >> 3, tid);
    } else if (bid < 480) {
        int lid = bid - 464;
        transpose_tile2(W_out, WoutT, Hz, Fz, lid & 1, lid >> 1, tid);
    } else if (bid == 480) {              // pairlist
        __shared__ int cnt[64];
        __shared__ int off[64];
        int i = tid;
        if (i < 64) {
            int c = 0;
            for (int j = i + 1; j < 64; ++j)
                if (present[i * 64 + j] != 0) c++;
            cnt[i] = c;
        }
        __syncthreads();
        if (i == 0) {
            int t = 0;
            for (int r = 0; r < 64; ++r) { off[r] = t; t += cnt[r]; }
            plist[0] = (unsigned)t;
        }
        __syncthreads();
        if (i < 64) {
            int o = 1 + off[i];
            for (int j = i + 1; j < 64; ++j)
                if (present[i * 64 + j] != 0) plist[o++] = (unsigned)(i * 64 + j);
        }
    } else if (bid == 481) {              // bocomb
        int c = tid;
        if (c < 64) {
            float a = b_out[c];
            for (int j = 0; j < 256; ++j) a = fmaf(bo[j], W_out[(size_t)j * 64 + c], a);
            bocomb[c] = a;
        }
    } else if (bid < 484) {               // bkv
        int c = tid;
        const float* Wx = (bid == 482) ? Wk : Wv;
        const float* bx = (bid == 482) ? bk : bv;
        float a = bx[c];
        for (int j = 0; j < 256; ++j) a = fmaf(b_ad[j], Wx[(size_t)j * Hz + c], a);
        bkv[(bid - 482) * 256 + c] = a;
    } else {                              // WadB bf16 copy
        int lid = bid - 484;
        int base = lid * 1024 + tid * 4;
        #pragma unroll
        for (int j = 0; j < 4; ++j) WadB[base + j] = f2bf_rne(W_ad[base + j]);
    }
}

// combo1: WoWoutT(2) | WadkvT(24) | pooled2(4) | mask(2048) | pe(1024)
__global__ __launch_bounds__(256) void combo1_kernel(
    const unsigned short* __restrict__ WoutT, const unsigned short* __restrict__ WoT,
    unsigned short* __restrict__ WoWoutT,
    const unsigned short* __restrict__ WkT, const unsigned short* __restrict__ WadB,
    unsigned short* __restrict__ WadkvT,
    const float* __restrict__ sapE, const float* __restrict__ W_sap,
    const float* __restrict__ b_sap, float* __restrict__ pooled,
    const float* __restrict__ batch_data, const float* __restrict__ mask_probs,
    unsigned short* __restrict__ safe_bf, float* __restrict__ stoch_out,
    unsigned long long* __restrict__ mask64,
    const float* __restrict__ pair_emb, const unsigned int* __restrict__ plist,
    unsigned short* __restrict__ Pe)
{
    __shared__ unsigned short smem[10240];   // 20 KB
    const int bid = blockIdx.x;
    const int tid = threadIdx.x;
    if (bid < 2) {
        gemm2_body<64, 128, true, 3>(smem, WoutT, WoT, nullptr, nullptr,
                                     WoWoutT, 64, Hz, Hz, bid, 0, tid);
    } else if (bid < 26) {
        int lid = bid - 2;
        gemm2_body<128, 128, true, 3>(smem, WkT, WadB, nullptr, nullptr,
                                      WadkvT, 512, Dz, Hz, lid % 6, lid / 6, tid);
    } else if (bid < 30) {
        pooled_body(smem, sapE, W_sap, b_sap, pooled, bid - 26, tid);
    } else if (bid < 2078) {
        mask_body(batch_data, mask_probs, safe_bf, stoch_out, mask64, bid - 30, tid);
    } else {
        pe_body(pair_emb, plist, Pe, bid - 2078, tid);
    }
}

// combo2: queryGEMM(128) | wbuild(512) | PeWaT GEMM(32)
__global__ __launch_bounds__(256) void combo2_kernel(
    const unsigned short* __restrict__ safe_bf, const unsigned short* __restrict__ WnumT,
    const float* __restrict__ b_num, const float* __restrict__ pooled,
    unsigned short* __restrict__ qBF,
    const unsigned long long* __restrict__ mask64, const unsigned int* __restrict__ plist,
    unsigned long long* __restrict__ sel, float* __restrict__ inv_cnt,
    const unsigned short* __restrict__ WadkvT, const unsigned short* __restrict__ Pe,
    unsigned short* __restrict__ PeWaT)
{
    __shared__ unsigned short smem[10240];
    const int bid = blockIdx.x;
    const int tid = threadIdx.x;
    if (bid < 128) {
        gemm2_body<128, 128, true, 1>(smem, safe_bf, WnumT, b_num, pooled,
                                      qBF, BTz, Hz, Fz, bid & 1, bid >> 1, tid);
    } else if (bid < 640) {
        wbuild_body(smem, mask64, plist, sel, inv_cnt, bid - 128, tid);
    } else {
        int lid = bid - 640;   // 32 blocks: M=512 (by 0..3), N=1024 (bx 0..7)
        gemm2_body<128, 128, true, 3>(smem, WadkvT, Pe, nullptr, nullptr,
                                      PeWaT, 512, NPAIRPAD, Dz, lid & 7, lid >> 3, tid);
    }
}

// combo3: selkv hybrid GEMM(512) | qproj LDS GEMM(128)
__global__ __launch_bounds__(256) void combo3_kernel(
    const unsigned long long* __restrict__ sel, const unsigned short* __restrict__ PeWaT,
    const float* __restrict__ inv_cnt, const float* __restrict__ bkv,
    unsigned short* __restrict__ kvproj,
    const unsigned short* __restrict__ qBF, const unsigned short* __restrict__ WqT,
    const float* __restrict__ bq, unsigned short* __restrict__ qbb)
{
    __shared__ unsigned short smem[16384];   // 32 KB
    const int bid = blockIdx.x;
    const int tid = threadIdx.x;
    if (bid < 512) {
        gemm_selkv_body2(smem, sel, PeWaT, inv_cnt, bkv, kvproj,
                         bid & 3, bid >> 2, tid);
    } else {
        int lid = bid - 512;
        gemm2_body<128, 128, true, 0>(smem, qBF, WqT, bq, nullptr,
                                      qbb, BTz, Hz, Hz, lid & 1, lid >> 1, tid);
    }
}

// Fused attention: QK^T -> softmax -> PV (PV in 64-key chunks).
__global__ __launch_bounds__(256) void attn_fused_kernel(
    const unsigned short* __restrict__ q, const unsigned short* __restrict__ kp,
    unsigned short* __restrict__ probs, unsigned short* __restrict__ pv)
{
    int blk = blockIdx.x;
    int bh = blk >> 1, half = blk & 1;
    int b = bh >> 2, h = bh & 3;
    __shared__ unsigned short smem[128 * QKPAD + 256 * QKPAD];
    unsigned short* Ql = smem;
    unsigned short* Kl = smem + 128 * QKPAD;
    const int tid = threadIdx.x;

    const unsigned short* qbase = q + (size_t)(b * Tz + half * 128) * Hz + h * HDz;
    #pragma unroll
    for (int i = 0; i < 4; ++i) {
        int e = tid + i * 256;
        int r = e >> 3, c8 = e & 7;
        *(ushort8v*)&Ql[r * QKPAD + c8 * 8] =
            *(const ushort8v*)(qbase + (size_t)r * Hz + c8 * 8);
    }
    const unsigned short* kbase = kp + (size_t)(b * Tz) * 512 + h * HDz;
    #pragma unroll
    for (int i = 0; i < 8; ++i) {
        int e = tid + i * 256;
        int r = e >> 3, c8 = e & 7;
        *(ushort8v*)&Kl[r * QKPAD + c8 * 8] =
            *(const ushort8v*)(kbase + (size_t)r * 512 + c8 * 8);
    }
    __syncthreads();

    const int lane = tid & 63, wave = tid >> 6;
    const int l15 = lane & 15, g = lane >> 4;

    f32x4 acc[2][16] = {};
    #pragma unroll
    for (int ks = 0; ks < 2; ++ks) {
        short8v a0 = *(const short8v*)&Ql[(wave * 32 + l15) * QKPAD + ks * 32 + g * 8];
        short8v a1 = *(const short8v*)&Ql[(wave * 32 + 16 + l15) * QKPAD + ks * 32 + g * 8];
        #pragma unroll
        for (int n = 0; n < 16; ++n) {
            short8v bn = *(const short8v*)&Kl[(n * 16 + l15) * QKPAD + ks * 32 + g * 8];
            acc[0][n] = __builtin_amdgcn_mfma_f32_16x16x32_bf16(a0, bn, acc[0][n], 0, 0, 0);
            acc[1][n] = __builtin_amdgcn_mfma_f32_16x16x32_bf16(a1, bn, acc[1][n], 0, 0, 0);
        }
    }

    #pragma unroll
    for (int m = 0; m < 2; ++m) {
        #pragma unroll
        for (int rr = 0; rr < 4; ++rr) {
            float mx = -1e30f;
            #pragma unroll
            for (int n = 0; n < 16; ++n) mx = fmaxf(mx, acc[m][n][rr]);
            #pragma unroll
            for (int s = 1; s < 16; s <<= 1) mx = fmaxf(mx, __shfl_xor(mx, s));
            float sum = 0.0f;
            #pragma unroll
            for (int n = 0; n < 16; ++n) {
                float e = __expf(0.125f * (acc[m][n][rr] - mx));
                acc[m][n][rr] = e;
                sum += e;
            }
            #pragma unroll
            for (int s = 1; s < 16; s <<= 1) sum += __shfl_xor(sum, s);
            float inv = 1.0f / sum;
            int row = half * 128 + wave * 32 + m * 16 + g * 4 + rr;
            unsigned short* dst = probs + ((size_t)bh * Tz + row) * Tz;
            #pragma unroll
            for (int n = 0; n < 16; ++n) {
                float p = acc[m][n][rr] * inv;
                acc[m][n][rr] = p;
                dst[n * 16 + l15] = f2bf_rne(p);
            }
        }
    }
    __syncthreads();

    unsigned short* Vt = smem;                 // [64][VTPAD]
    unsigned short* Pl = smem + 64 * VTPAD;    // [128][PLPAD=72]
    const unsigned short* vbase = kp + (size_t)(b * Tz) * 512 + 256 + h * HDz;
    #pragma unroll
    for (int i = 0; i < 8; ++i) {
        int e = tid + i * 256;
        int key = e >> 3, c8 = e & 7;
        ushort8v v8 = *(const ushort8v*)(vbase + (size_t)key * 512 + c8 * 8);
        #pragma unroll
        for (int j = 0; j < 8; ++j)
            Vt[(c8 * 8 + j) * VTPAD + key] = v8[j];
    }

    f32x4 accpv[2][4] = {};
    for (int ks = 0; ks < 4; ++ks) {          // 64-key chunks
        #pragma unroll
        for (int m = 0; m < 2; ++m) {
            #pragma unroll
            for (int rr = 0; rr < 4; ++rr) {
                int row = wave * 32 + m * 16 + g * 4 + rr;
                #pragma unroll
                for (int j = 0; j < 4; ++j)
                    Pl[row * PLPAD + j * 16 + l15] = f2bf_rne(acc[m][4 * ks + j][rr]);
            }
        }
        __syncthreads();   // Vt ready (1st iter) + Pl ready
        #pragma unroll
        for (int kk = 0; kk < 2; ++kk) {
            short8v a0 = *(const short8v*)&Pl[(wave * 32 + l15) * PLPAD + kk * 32 + g * 8];
            short8v a1 = *(const short8v*)&Pl[(wave * 32 + 16 + l15) * PLPAD + kk * 32 + g * 8];
            #pragma unroll
            for (int n = 0; n < 4; ++n) {
                short8v bn = *(const short8v*)&Vt[(n * 16 + l15) * VTPAD + ks * 64 + kk * 32 + g * 8];
                accpv[0][n] = __builtin_amdgcn_mfma_f32_16x16x32_bf16(a0, bn, accpv[0][n], 0, 0, 0);
                accpv[1][n] = __builtin_amdgcn_mfma_f32_16x16x32_bf16(a1, bn, accpv[1][n], 0, 0, 0);
            }
        }
        __syncthreads();
    }

    #pragma unroll
    for (int m = 0; m < 2; ++m) {
        #pragma unroll
        for (int rr = 0; rr < 4; ++rr) {
            int row = b * Tz + half * 128 + wave * 32 + m * 16 + g * 4 + rr;
            #pragma unroll
            for (int n = 0; n < 4; ++n)
                pv[(size_t)row * Hz + h * HDz + n * 16 + l15] = f2bf_rne(accpv[m][n][rr]);
        }
    }
}

// combo4: meanheads(1024) | final(128)
__global__ __launch_bounds__(256) void combo4_kernel(
    const unsigned short* __restrict__ probs, float* __restrict__ out_attn,
    const unsigned short* __restrict__ qBF, const unsigned short* __restrict__ pvb,
    const unsigned short* __restrict__ WoutT, const unsigned short* __restrict__ WoWoutT,
    const float* __restrict__ bocomb, float* __restrict__ out_imputed)
{
    __shared__ unsigned short smem[5120];
    const int bid = blockIdx.x;
    const int tid = threadIdx.x;
    if (bid < 1024) {
        meanheads_body(probs, out_attn, bid, tid);
    } else {
        final_body(smem, qBF, pvb, WoutT, WoWoutT, bocomb, out_imputed, bid - 1024, tid);
    }
}

// ---------------------------------------------------------------------------
extern "C" void kernel_launch(void* const* d_in, const int* in_sizes, int n_in,
                              void* d_out, int out_size, void* d_ws, size_t ws_size,
                              hipStream_t stream)
{
    const float* batch_data = (const float*)d_in[0];
    const float* mask_probs = (const float*)d_in[1];
    const float* sapE       = (const float*)d_in[2];
    const float* pair_emb   = (const float*)d_in[3];
    const int*   pair_present = (const int*)d_in[4];
    const float* W_num = (const float*)d_in[5];  const float* b_num = (const float*)d_in[6];
    const float* W_sap = (const float*)d_in[7];  const float* b_sap = (const float*)d_in[8];
    const float* W_ad  = (const float*)d_in[9];  const float* b_ad  = (const float*)d_in[10];
    const float* Wq = (const float*)d_in[11]; const float* bq = (const float*)d_in[12];
    const float* Wk = (const float*)d_in[13]; const float* bk = (const float*)d_in[14];
    const float* Wv = (const float*)d_in[15]; const float* bv = (const float*)d_in[16];
    const float* Wo = (const float*)d_in[17]; const float* bo = (const float*)d_in[18];
    const float* W_out = (const float*)d_in[19]; const float* b_out = (const float*)d_in[20];

    float* out = (float*)d_out;
    float* out_imputed = out;                 // [B,T,F]
    float* out_stoch   = out + 524288;        // [B,T,F]
    float* out_attn    = out + 1048576;       // [B,T,T]

    float* ws = (float*)d_ws;
    unsigned short* safe_bf = (unsigned short*)ws;             // bf16 [8192][64]
    unsigned short* qBF   = (unsigned short*)(ws + 524288);    // bf16 [8192][256]
    unsigned short* probs = (unsigned short*)(ws + 2621440);   // bf16 [128][256][256]
    unsigned long long* sel = (unsigned long long*)(ws + 9961472); // u64 [8192][16]
    unsigned short* qbb   = (unsigned short*)(ws + 11010048);  // bf16 [8192][256]
    unsigned short* Pe    = (unsigned short*)(ws + 15204352);  // bf16 [1024][768] (dead after combo2)
    unsigned short* kvproj = (unsigned short*)(ws + 15204352); // bf16 [8192][512] (over dead Pe)
    unsigned short* pvb   = (unsigned short*)(ws + 17301504);  // bf16 [8192][256]
    unsigned short* WoWoutT = (unsigned short*)(ws + 18350080);// bf16 [64][256]
    float* bocomb = ws + 18358272;                             // 64 f32
    float* bkv    = ws + 18358336;                             // 512 f32
    float* inv_cnt = ws + 18358848;                            // 8192 f32
    unsigned short* WadkvT = (unsigned short*)(ws + 18367040); // bf16 [512][768]
    unsigned short* WadB   = (unsigned short*)(ws + 18563648); // bf16 [768][256]
    unsigned short* PeWaT  = (unsigned short*)(ws + 18661952); // bf16 [512][1024]
    float* pooled = ws + 19398656;
    unsigned long long* mask64 = (unsigned long long*)(ws + 19398912);
    unsigned int* plist = (unsigned int*)(ws + 19415296);

    unsigned short* wT = (unsigned short*)(ws + 19419392);
    unsigned short* WnumT = wT;                  // [256][64]
    unsigned short* WadT  = wT + 16384;          // [256][768]
    unsigned short* WqT   = wT + 212992;         // [256][256]
    unsigned short* WkT   = wT + 278528;         // (WkT,WvT contiguous)
    unsigned short* WvT   = wT + 344064;
    unsigned short* WoT   = wT + 409600;
    unsigned short* WoutT = wT + 475136;         // [64][256]

    // 1. prep
    prep_kernel<<<676, 256, 0, stream>>>(
        W_num, W_ad, Wq, Wk, Wv, Wo, W_out, bo, b_out, b_ad, bk, bv, pair_present,
        WnumT, WadT, WqT, WkT, WvT, WoT, WoutT, bocomb, bkv, WadB, plist);
    // 2. combo1: WoWoutT | WadkvT | pooled | mask | Pe gather
    combo1_kernel<<<3102, 256, 0, stream>>>(
        WoutT, WoT, WoWoutT, WkT, WadB, WadkvT,
        sapE, W_sap, b_sap, pooled,
        batch_data, mask_probs, safe_bf, out_stoch, mask64,
        pair_emb, plist, Pe);
    // 3. combo2: query GEMM | wbuild | PeWaT = WadkvT @ Pe^T
    combo2_kernel<<<672, 256, 0, stream>>>(
        safe_bf, WnumT, b_num, pooled, qBF,
        mask64, plist, sel, inv_cnt, WadkvT, Pe, PeWaT);
    // 4. combo3: selkv hybrid GEMM (reg-A + chunked swizzled LDS-B) | qproj
    combo3_kernel<<<640, 256, 0, stream>>>(
        sel, PeWaT, inv_cnt, bkv, kvproj, qBF, WqT, bq, qbb);
    // 5. fused attention
    attn_fused_kernel<<<256, 256, 0, stream>>>(qbb, kvproj, probs, pvb);
    // 6. combo4: meanheads | final
    combo4_kernel<<<1152, 256, 0, stream>>>(
        probs, out_attn, qBF, pvb, WoutT, WoWoutT, bocomb, out_imputed);
}

// Round 14
// 119.613 us; speedup vs baseline: 1.2648x; 1.0403x over previous
//
#include <hip/hip_runtime.h>
#include <hip/hip_bf16.h>

// Shapes
#define Bz 32
#define Tz 256
#define Fz 64
#define Dz 768
#define Sz 768
#define Hz 256
#define NHz 4
#define HDz 64
#define BTz 8192  // B*T
#define NPAIRPAD 1024
#define QKPAD 72   // bf16 units; 144B row stride: 2-way bank alias (free)
#define VTPAD 264
#define PLPAD 72   // PV 64-key chunk
#define BQPAD 264

typedef __attribute__((ext_vector_type(8))) short short8v;
typedef __attribute__((ext_vector_type(8))) unsigned short ushort8v;
typedef __attribute__((ext_vector_type(4))) float f32x4;

__device__ inline unsigned short f2bf_rne(float x) {
    unsigned u = __float_as_uint(x);
    unsigned r = (u + 0x7fffu + ((u >> 16) & 1u)) >> 16;
    return (unsigned short)r;
}
__device__ inline float bf2f(unsigned short x) {
    return __uint_as_float(((unsigned)x) << 16);
}
__device__ inline short8v expand8(unsigned bits) {
    short8v r;
    #pragma unroll
    for (int j = 0; j < 8; ++j)
        r[j] = (bits & (1u << j)) ? (short)0x3f80 : (short)0;
    return r;
}

// ===========================================================================
// Device bodies
// ===========================================================================

// Unified LDS-staged MFMA GEMM body.
template <int BM, int BN, bool OUTBF16, int B2MODE>
__device__ __forceinline__ void gemm2_body(
    unsigned short* __restrict__ smem,
    const unsigned short* __restrict__ A,
    const unsigned short* __restrict__ Bt,
    const float* __restrict__ bias, const float* __restrict__ bias2,
    void* __restrict__ Cv, int M, int N, int K, int bx, int by, int tid)
{
    constexpr int WC = BN / 64;
    constexpr int WR = 4 / WC;
    constexpr int RW = BM / WR;
    constexpr int MT = RW / 16;
    constexpr int NT = 4;
    unsigned short* As = smem;
    unsigned short* Bs = smem + BM * 40;
    const int lane = tid & 63, wave = tid >> 6;
    const int l15 = lane & 15, g = lane >> 4;
    const int wr = wave / WC, wc = wave % WC;
    const int row0 = by * BM, col0 = bx * BN;

    f32x4 acc[MT][NT] = {};

    for (int k0 = 0; k0 < K; k0 += 32) {
        __syncthreads();
        #pragma unroll
        for (int i = 0; i < BM * 4 / 256; ++i) {
            int e = tid + i * 256;
            int r = e >> 2, c8 = e & 3;
            *(ushort8v*)(As + r * 40 + c8 * 8) =
                *(const ushort8v*)(A + (size_t)(row0 + r) * K + k0 + c8 * 8);
        }
        #pragma unroll
        for (int i = 0; i < BN * 4 / 256; ++i) {
            int e = tid + i * 256;
            int n = e >> 2, c = e & 3;
            *(ushort8v*)(Bs + n * 40 + c * 8) =
                *(const ushort8v*)(Bt + (size_t)(col0 + n) * K + k0 + c * 8);
        }
        __syncthreads();

        short8v a[MT], b[NT];
        #pragma unroll
        for (int m = 0; m < MT; ++m)
            a[m] = *(const short8v*)(As + (wr * RW + m * 16 + l15) * 40 + g * 8);
        #pragma unroll
        for (int n = 0; n < NT; ++n)
            b[n] = *(const short8v*)(Bs + (wc * 64 + n * 16 + l15) * 40 + g * 8);
        #pragma unroll
        for (int m = 0; m < MT; ++m)
            #pragma unroll
            for (int n = 0; n < NT; ++n)
                acc[m][n] = __builtin_amdgcn_mfma_f32_16x16x32_bf16(a[m], b[n], acc[m][n], 0, 0, 0);
    }

    #pragma unroll
    for (int m = 0; m < MT; ++m) {
        #pragma unroll
        for (int rr = 0; rr < 4; ++rr) {
            int row = row0 + wr * RW + m * 16 + g * 4 + rr;
            #pragma unroll
            for (int n = 0; n < NT; ++n) {
                int col = col0 + wc * 64 + n * 16 + l15;
                float o = acc[m][n][rr];
                if (B2MODE == 2) {
                    o += (col < (N >> 1)) ? bias[col] : bias2[col - (N >> 1)];
                } else if (B2MODE != 3) {
                    o += bias[col];
                    if (B2MODE == 1) o += bias2[col];
                }
                if (OUTBF16) ((unsigned short*)Cv)[(size_t)row * N + col] = f2bf_rne(o);
                else         ((float*)Cv)[(size_t)row * N + col] = o;
            }
        }
    }
}

// selkv hybrid GEMM (R13-proven): A from sel bits in regs, B chunked+swizzled LDS.
__device__ __forceinline__ void gemm_selkv_body2(
    unsigned short* __restrict__ smem,         // >= 128*128 ushorts (32 KB)
    const unsigned long long* __restrict__ sel,
    const unsigned short* __restrict__ Bt,     // PeWaT [512][1024]
    const float* __restrict__ rs,              // inv_cnt [8192]
    const float* __restrict__ bias,            // bkv [512]
    unsigned short* __restrict__ C,            // kvproj [8192][512]
    int bx, int by, int tid)
{
    unsigned short* Bs = smem;
    const int lane = tid & 63, wave = tid >> 6;
    const int l15 = lane & 15, g = lane >> 4;
    const int wr = wave >> 1, wc = wave & 1;
    const int row0 = by * 64, col0 = bx * 128;

    const unsigned long long* selr0 = sel + (size_t)(row0 + wr * 32 + l15) * 16;
    const unsigned long long* selr1 = selr0 + 16 * 16;

    f32x4 acc[2][4] = {};

    for (int kc = 0; kc < 1024; kc += 128) {
        __syncthreads();
        #pragma unroll
        for (int i = 0; i < 8; ++i) {
            int e = tid + i * 256;
            int r = e >> 4, c8 = e & 15;
            int slot = c8 ^ (r & 7);
            *(ushort8v*)(Bs + r * 128 + slot * 8) =
                *(const ushort8v*)(Bt + (size_t)(col0 + r) * 1024 + kc + c8 * 8);
        }
        __syncthreads();

        #pragma unroll
        for (int kk = 0; kk < 4; ++kk) {
            const int k0 = kc + kk * 32;
            const int word = k0 >> 6;
            const int shift = (k0 & 32) + g * 8;
            short8v a0 = expand8((unsigned)(selr0[word] >> shift) & 0xFFu);
            short8v a1 = expand8((unsigned)(selr1[word] >> shift) & 0xFFu);
            #pragma unroll
            for (int n = 0; n < 4; ++n) {
                int row = wc * 64 + n * 16 + l15;
                int slot = (kk * 4 + g) ^ (row & 7);
                short8v bn = *(const short8v*)(Bs + row * 128 + slot * 8);
                acc[0][n] = __builtin_amdgcn_mfma_f32_16x16x32_bf16(a0, bn, acc[0][n], 0, 0, 0);
                acc[1][n] = __builtin_amdgcn_mfma_f32_16x16x32_bf16(a1, bn, acc[1][n], 0, 0, 0);
            }
        }
    }

    #pragma unroll
    for (int m = 0; m < 2; ++m) {
        #pragma unroll
        for (int rr = 0; rr < 4; ++rr) {
            int row = row0 + wr * 32 + m * 16 + g * 4 + rr;
            float s = rs[row];
            #pragma unroll
            for (int n = 0; n < 4; ++n) {
                int col = col0 + wc * 64 + n * 16 + l15;
                C[(size_t)row * 512 + col] = f2bf_rne(acc[m][n][rr] * s + bias[col]);
            }
        }
    }
}

// masking body
__device__ __forceinline__ void mask_body(
    const float* __restrict__ bd, const float* __restrict__ mp,
    unsigned short* __restrict__ safe_bf, float* __restrict__ stoch_out,
    unsigned long long* __restrict__ mask64, int bid, int tid)
{
    int idx = bid * 256 + tid;
    float x = bd[idx];
    float p = mp[idx];
    unsigned xb = __float_as_uint(x);
    bool valid = ((xb & 0x7fffffffu) <= 0x7f800000u);
    bool st = (p < 0.3f) && valid;
    bool sv = valid && !st;
    safe_bf[idx] = sv ? f2bf_rne(x) : 0;
    stoch_out[idx] = st ? 1.0f : 0.0f;
    unsigned long long m = __ballot(sv);
    if ((tid & 63) == 0) mask64[idx >> 6] = m;
}

// pooled body
__device__ __forceinline__ void pooled_body(
    unsigned short* __restrict__ smem,
    const float* __restrict__ E, const float* __restrict__ W_sap,
    const float* __restrict__ b_sap, float* __restrict__ pooled, int bid, int tid)
{
    float* colmean = (float*)smem;
    float* red = colmean + Sz;
    for (int s = tid; s < Sz; s += 256) {
        float a = 0.0f;
        #pragma unroll 8
        for (int f = 0; f < Fz; ++f) a += E[(size_t)f * Sz + s];
        colmean[s] = a * (1.0f / 64.0f);
    }
    __syncthreads();
    const int hl = tid & 63, sg = tid >> 6;
    const int h = bid * 64 + hl;
    float acc = 0.0f;
    #pragma unroll 4
    for (int s = sg; s < Sz; s += 4)
        acc = fmaf(colmean[s], W_sap[(size_t)s * Hz + h], acc);
    red[sg * 64 + hl] = acc;
    __syncthreads();
    if (sg == 0)
        pooled[h] = b_sap[h] + ((red[hl] + red[64 + hl]) + (red[128 + hl] + red[192 + hl]));
}

// wbuild body
__device__ __forceinline__ void wbuild_body(
    unsigned short* __restrict__ smem,
    const unsigned long long* __restrict__ mask64,
    const unsigned int* __restrict__ plist,
    unsigned long long* __restrict__ sel, float* __restrict__ inv_cnt,
    int bid, int tid)
{
    unsigned int* pl = (unsigned int*)smem;
    for (int i = tid; i < NPAIRPAD; i += 256) pl[i] = plist[1 + i];
    __syncthreads();
    const int np = (int)plist[0];
    const int btl = tid >> 4, w = tid & 15;
    const int bt = bid * 16 + btl;
    unsigned long long m = mask64[bt];
    unsigned long long word = 0ull;
    int pbase = w * 64;
    int jmax = min(64, np - pbase);
    for (int j = 0; j < jmax; ++j) {
        unsigned ij = pl[pbase + j];
        unsigned long long bit = (m >> (ij >> 6)) & (m >> (ij & 63)) & 1ull;
        word |= bit << j;
    }
    sel[(size_t)bt * 16 + w] = word;
    int c = __popcll(word);
    #pragma unroll
    for (int s = 1; s < 16; s <<= 1) c += __shfl_xor(c, s);
    if (w == 0) inv_cnt[bt] = c > 0 ? 1.0f / (float)c : 0.0f;
}

// pe body
__device__ __forceinline__ void pe_body(
    const float* __restrict__ pair_emb, const unsigned int* __restrict__ plist,
    unsigned short* __restrict__ Pe, int p, int t)
{
    int np = (int)plist[0];
    if (p < np) {
        unsigned ij = plist[1 + p];
        const float* src = pair_emb + (size_t)ij * Dz;
        #pragma unroll
        for (int c = 0; c < 3; ++c)
            Pe[(size_t)p * Dz + t + c * 256] = f2bf_rne(src[t + c * 256]);
    } else {
        #pragma unroll
        for (int c = 0; c < 3; ++c)
            Pe[(size_t)p * Dz + t + c * 256] = 0;
    }
}

// meanheads body
__device__ __forceinline__ void meanheads_body(
    const unsigned short* __restrict__ probs, float* __restrict__ out3,
    int bid, int tid)
{
    int idx = bid * 256 + tid;
    int tk8 = idx & 31;
    int btq = idx >> 5;
    int b = btq >> 8, tq = btq & 255;
    float acc[8] = {};
    #pragma unroll
    for (int h = 0; h < 4; ++h) {
        int bh = b * 4 + h;
        ushort8v p = *(const ushort8v*)&probs[(((size_t)bh * Tz + tq) << 8) + tk8 * 8];
        #pragma unroll
        for (int j = 0; j < 8; ++j) acc[j] += bf2f(p[j]) * 0.25f;
    }
    float* dst = out3 + ((size_t)btq << 8) + tk8 * 8;
    float4 o0 = {acc[0], acc[1], acc[2], acc[3]};
    float4 o1 = {acc[4], acc[5], acc[6], acc[7]};
    *(float4*)dst = o0;
    *(float4*)(dst + 4) = o1;
}

// final body
__device__ __forceinline__ void final_body(
    unsigned short* __restrict__ smem,
    const unsigned short* __restrict__ qBF, const unsigned short* __restrict__ pvb,
    const unsigned short* __restrict__ WoutT, const unsigned short* __restrict__ WWT,
    const float* __restrict__ bias, float* __restrict__ C, int bid, int tid)
{
    unsigned short* As = smem;
    unsigned short* Bs = smem + 64 * 40;
    const int lane = tid & 63, wave = tid >> 6;
    const int l15 = lane & 15, g = lane >> 4;
    const int row0 = bid * 64;

    f32x4 acc[4] = {};

    for (int ph = 0; ph < 2; ++ph) {
        const unsigned short* Am = ph == 0 ? qBF : pvb;
        const unsigned short* Bm = ph == 0 ? WoutT : WWT;
        for (int k0 = 0; k0 < 256; k0 += 32) {
            __syncthreads();
            {
                int r = tid >> 2, c8 = tid & 3;
                *(ushort8v*)(As + r * 40 + c8 * 8) =
                    *(const ushort8v*)(Am + (size_t)(row0 + r) * Hz + k0 + c8 * 8);
                *(ushort8v*)(Bs + r * 40 + c8 * 8) =
                    *(const ushort8v*)(Bm + (size_t)r * Hz + k0 + c8 * 8);
            }
            __syncthreads();
            short8v a = *(const short8v*)(As + (wave * 16 + l15) * 40 + g * 8);
            #pragma unroll
            for (int n = 0; n < 4; ++n) {
                short8v bn = *(const short8v*)(Bs + (n * 16 + l15) * 40 + g * 8);
                acc[n] = __builtin_amdgcn_mfma_f32_16x16x32_bf16(a, bn, acc[n], 0, 0, 0);
            }
        }
    }

    #pragma unroll
    for (int rr = 0; rr < 4; ++rr) {
        int row = row0 + wave * 16 + g * 4 + rr;
        #pragma unroll
        for (int n = 0; n < 4; ++n) {
            int col = n * 16 + l15;
            C[(size_t)row * Fz + col] = acc[n][rr] + bias[col];
        }
    }
}

// ===========================================================================
// Kernels
// ===========================================================================

__device__ inline void transpose_tile2(const float* __restrict__ in,
                                       unsigned short* __restrict__ out,
                                       int R, int C, int bx, int by, int tid)
{
    __shared__ float t[32][33];
    const int c0 = bx * 32, r0 = by * 32;
    const int lc = tid & 31, lr8 = tid >> 5;
    #pragma unroll
    for (int i = 0; i < 4; ++i) {
        int r = lr8 + i * 8;
        t[r][lc] = in[(size_t)(r0 + r) * C + c0 + lc];
    }
    __syncthreads();
    #pragma unroll
    for (int i = 0; i < 4; ++i) {
        int oc = lr8 + i * 8;
        out[(size_t)(c0 + oc) * R + r0 + lc] = f2bf_rne(t[lc][oc]);
    }
}

// prep: WkT(64) | WvT(64) | WoT(64) | WoutT(16) | WadB(192) | plist(1) = 401
__global__ __launch_bounds__(256) void prep_kernel(
    const float* __restrict__ Wk, const float* __restrict__ Wv,
    const float* __restrict__ Wo, const float* __restrict__ W_out,
    const float* __restrict__ W_ad, const int* __restrict__ present,
    unsigned short* __restrict__ WkT, unsigned short* __restrict__ WvT,
    unsigned short* __restrict__ WoT, unsigned short* __restrict__ WoutT,
    unsigned short* __restrict__ WadB, unsigned int* __restrict__ plist)
{
    const int bid = blockIdx.x;
    const int tid = threadIdx.x;
    if (bid < 64) {
        transpose_tile2(Wk, WkT, Hz, Hz, bid & 7, bid >> 3, tid);
    } else if (bid < 128) {
        int lid = bid - 64;
        transpose_tile2(Wv, WvT, Hz, Hz, lid & 7, lid >> 3, tid);
    } else if (bid < 192) {
        int lid = bid - 128;
        transpose_tile2(Wo, WoT, Hz, Hz, lid & 7, lid >> 3, tid);
    } else if (bid < 208) {
        int lid = bid - 192;
        transpose_tile2(W_out, WoutT, Hz, Fz, lid & 1, lid >> 1, tid);
    } else if (bid < 400) {               // WadB bf16 copy (192 blocks)
        int lid = bid - 208;
        int base = lid * 1024 + tid * 4;
        #pragma unroll
        for (int j = 0; j < 4; ++j) WadB[base + j] = f2bf_rne(W_ad[base + j]);
    } else {                              // pairlist
        __shared__ int cnt[64];
        __shared__ int off[64];
        int i = tid;
        if (i < 64) {
            int c = 0;
            for (int j = i + 1; j < 64; ++j)
                if (present[i * 64 + j] != 0) c++;
            cnt[i] = c;
        }
        __syncthreads();
        if (i == 0) {
            int t = 0;
            for (int r = 0; r < 64; ++r) { off[r] = t; t += cnt[r]; }
            plist[0] = (unsigned)t;
        }
        __syncthreads();
        if (i < 64) {
            int o = 1 + off[i];
            for (int j = i + 1; j < 64; ++j)
                if (present[i * 64 + j] != 0) plist[o++] = (unsigned)(i * 64 + j);
        }
    }
}

// combo1: WoWoutT(2) | WadkvT(24) | pooled2(4) | mask(2048) | pe(1024)
//       | WnumT(16) | WqT(64) | bocomb(1) | bkv(2)  = 3185 blocks
__global__ __launch_bounds__(256) void combo1_kernel(
    const unsigned short* __restrict__ WoutT, const unsigned short* __restrict__ WoT,
    unsigned short* __restrict__ WoWoutT,
    const unsigned short* __restrict__ WkT, const unsigned short* __restrict__ WadB,
    unsigned short* __restrict__ WadkvT,
    const float* __restrict__ sapE, const float* __restrict__ W_sap,
    const float* __restrict__ b_sap, float* __restrict__ pooled,
    const float* __restrict__ batch_data, const float* __restrict__ mask_probs,
    unsigned short* __restrict__ safe_bf, float* __restrict__ stoch_out,
    unsigned long long* __restrict__ mask64,
    const float* __restrict__ pair_emb, const unsigned int* __restrict__ plist,
    unsigned short* __restrict__ Pe,
    const float* __restrict__ W_num, unsigned short* __restrict__ WnumT,
    const float* __restrict__ Wq, unsigned short* __restrict__ WqT,
    const float* __restrict__ bo, const float* __restrict__ b_out,
    const float* __restrict__ W_out, float* __restrict__ bocomb,
    const float* __restrict__ b_ad, const float* __restrict__ bk,
    const float* __restrict__ bv, const float* __restrict__ Wk,
    const float* __restrict__ Wv, float* __restrict__ bkv)
{
    __shared__ unsigned short smem[10240];   // 20 KB
    const int bid = blockIdx.x;
    const int tid = threadIdx.x;
    if (bid < 2) {
        gemm2_body<64, 128, true, 3>(smem, WoutT, WoT, nullptr, nullptr,
                                     WoWoutT, 64, Hz, Hz, bid, 0, tid);
    } else if (bid < 26) {
        int lid = bid - 2;
        gemm2_body<128, 128, true, 3>(smem, WkT, WadB, nullptr, nullptr,
                                      WadkvT, 512, Dz, Hz, lid % 6, lid / 6, tid);
    } else if (bid < 30) {
        pooled_body(smem, sapE, W_sap, b_sap, pooled, bid - 26, tid);
    } else if (bid < 2078) {
        mask_body(batch_data, mask_probs, safe_bf, stoch_out, mask64, bid - 30, tid);
    } else if (bid < 3102) {
        pe_body(pair_emb, plist, Pe, bid - 2078, tid);
    } else if (bid < 3118) {
        int lid = bid - 3102;
        transpose_tile2(W_num, WnumT, Fz, Hz, lid & 7, lid >> 3, tid);
    } else if (bid < 3182) {
        int lid = bid - 3118;
        transpose_tile2(Wq, WqT, Hz, Hz, lid & 7, lid >> 3, tid);
    } else if (bid == 3182) {             // bocomb
        int c = tid;
        if (c < 64) {
            float a = b_out[c];
            for (int j = 0; j < 256; ++j) a = fmaf(bo[j], W_out[(size_t)j * 64 + c], a);
            bocomb[c] = a;
        }
    } else {                              // bkv (2 blocks)
        int c = tid;
        const float* Wx = (bid == 3183) ? Wk : Wv;
        const float* bx = (bid == 3183) ? bk : bv;
        float a = bx[c];
        for (int j = 0; j < 256; ++j) a = fmaf(b_ad[j], Wx[(size_t)j * Hz + c], a);
        bkv[(bid - 3183) * 256 + c] = a;
    }
}

// combo2: queryGEMM(128) | wbuild(512) | PeWaT GEMM(32)
__global__ __launch_bounds__(256) void combo2_kernel(
    const unsigned short* __restrict__ safe_bf, const unsigned short* __restrict__ WnumT,
    const float* __restrict__ b_num, const float* __restrict__ pooled,
    unsigned short* __restrict__ qBF,
    const unsigned long long* __restrict__ mask64, const unsigned int* __restrict__ plist,
    unsigned long long* __restrict__ sel, float* __restrict__ inv_cnt,
    const unsigned short* __restrict__ WadkvT, const unsigned short* __restrict__ Pe,
    unsigned short* __restrict__ PeWaT)
{
    __shared__ unsigned short smem[10240];
    const int bid = blockIdx.x;
    const int tid = threadIdx.x;
    if (bid < 128) {
        gemm2_body<128, 128, true, 1>(smem, safe_bf, WnumT, b_num, pooled,
                                      qBF, BTz, Hz, Fz, bid & 1, bid >> 1, tid);
    } else if (bid < 640) {
        wbuild_body(smem, mask64, plist, sel, inv_cnt, bid - 128, tid);
    } else {
        int lid = bid - 640;
        gemm2_body<128, 128, true, 3>(smem, WadkvT, Pe, nullptr, nullptr,
                                      PeWaT, 512, NPAIRPAD, Dz, lid & 7, lid >> 3, tid);
    }
}

// combo3: selkv hybrid GEMM only (512 blocks)
__global__ __launch_bounds__(256) void combo3_kernel(
    const unsigned long long* __restrict__ sel, const unsigned short* __restrict__ PeWaT,
    const float* __restrict__ inv_cnt, const float* __restrict__ bkv,
    unsigned short* __restrict__ kvproj)
{
    __shared__ unsigned short smem[16384];   // 32 KB
    gemm_selkv_body2(smem, sel, PeWaT, inv_cnt, bkv, kvproj,
                     blockIdx.x & 3, blockIdx.x >> 2, threadIdx.x);
}

// Fused attention with in-kernel Q projection:
// Q_h = qBF @ WqT_h + bq  (4x 64-k LDS chunks) -> Ql; then QK^T/softmax/PV.
__global__ __launch_bounds__(256) void attn_fused_kernel(
    const unsigned short* __restrict__ qBF, const unsigned short* __restrict__ WqT,
    const float* __restrict__ bq, const unsigned short* __restrict__ kp,
    unsigned short* __restrict__ probs, unsigned short* __restrict__ pv)
{
    int blk = blockIdx.x;
    int bh = blk >> 1, half = blk & 1;
    int b = bh >> 2, h = bh & 3;
    __shared__ unsigned short smem[128 * QKPAD + 256 * QKPAD];  // 55296 B
    unsigned short* Ql = smem;                 // [128][QKPAD]  (9216 ushorts)
    unsigned short* Kl = smem + 128 * QKPAD;   // [256][QKPAD]
    unsigned short* Aq = smem;                 // qproj A chunk [128][QKPAD] (over Ql)
    unsigned short* Bq = smem + 128 * QKPAD;   // qproj B [64][BQPAD] (over Kl)
    const int tid = threadIdx.x;
    const int lane = tid & 63, wave = tid >> 6;
    const int l15 = lane & 15, g = lane >> 4;

    // --- phase 0: Q projection ---
    // stage Bq = WqT rows h*64..h*64+63, all 256 k  (64x256 -> 8 vec8/thread)
    {
        const unsigned short* src = WqT + (size_t)(h * 64) * Hz;
        #pragma unroll
        for (int i = 0; i < 8; ++i) {
            int e = tid + i * 256;
            int n = e >> 5, k8 = e & 31;
            *(ushort8v*)(Bq + n * BQPAD + k8 * 8) =
                *(const ushort8v*)(src + (size_t)n * Hz + k8 * 8);
        }
    }
    const unsigned short* abase = qBF + (size_t)(b * Tz + half * 128) * Hz;
    f32x4 acc_q[2][4] = {};
    for (int c = 0; c < 4; ++c) {            // 64-k chunks
        __syncthreads();                     // Aq reuse + (1st iter) Bq visibility
        #pragma unroll
        for (int i = 0; i < 4; ++i) {        // 128 rows x 8 vec8 of 64 k
            int e = tid + i * 256;
            int r = e >> 3, k8 = e & 7;
            *(ushort8v*)(Aq + r * QKPAD + k8 * 8) =
                *(const ushort8v*)(abase + (size_t)r * Hz + c * 64 + k8 * 8);
        }
        __syncthreads();
        #pragma unroll
        for (int kk = 0; kk < 2; ++kk) {
            short8v a0 = *(const short8v*)(Aq + (wave * 32 + l15) * QKPAD + kk * 32 + g * 8);
            short8v a1 = *(const short8v*)(Aq + (wave * 32 + 16 + l15) * QKPAD + kk * 32 + g * 8);
            #pragma unroll
            for (int n = 0; n < 4; ++n) {
                short8v bn = *(const short8v*)(Bq + (n * 16 + l15) * BQPAD + c * 64 + kk * 32 + g * 8);
                acc_q[0][n] = __builtin_amdgcn_mfma_f32_16x16x32_bf16(a0, bn, acc_q[0][n], 0, 0, 0);
                acc_q[1][n] = __builtin_amdgcn_mfma_f32_16x16x32_bf16(a1, bn, acc_q[1][n], 0, 0, 0);
            }
        }
    }
    __syncthreads();   // all Aq/Bq reads done (cross-wave Bq hazard)

    // write Q (+bias, cvt bf16) into Ql; stage K into Kl
    #pragma unroll
    for (int m = 0; m < 2; ++m) {
        #pragma unroll
        for (int rr = 0; rr < 4; ++rr) {
            int row = wave * 32 + m * 16 + g * 4 + rr;
            #pragma unroll
            for (int n = 0; n < 4; ++n) {
                int col = n * 16 + l15;
                Ql[row * QKPAD + col] = f2bf_rne(acc_q[m][n][rr] + bq[h * 64 + col]);
            }
        }
    }
    const unsigned short* kbase = kp + (size_t)(b * Tz) * 512 + h * HDz;
    #pragma unroll
    for (int i = 0; i < 8; ++i) {
        int e = tid + i * 256;
        int r = e >> 3, c8 = e & 7;
        *(ushort8v*)&Kl[r * QKPAD + c8 * 8] =
            *(const ushort8v*)(kbase + (size_t)r * 512 + c8 * 8);
    }
    __syncthreads();

    // --- phase 1: QK^T + softmax ---
    f32x4 acc[2][16] = {};
    #pragma unroll
    for (int ks = 0; ks < 2; ++ks) {
        short8v a0 = *(const short8v*)&Ql[(wave * 32 + l15) * QKPAD + ks * 32 + g * 8];
        short8v a1 = *(const short8v*)&Ql[(wave * 32 + 16 + l15) * QKPAD + ks * 32 + g * 8];
        #pragma unroll
        for (int n = 0; n < 16; ++n) {
            short8v bn = *(const short8v*)&Kl[(n * 16 + l15) * QKPAD + ks * 32 + g * 8];
            acc[0][n] = __builtin_amdgcn_mfma_f32_16x16x32_bf16(a0, bn, acc[0][n], 0, 0, 0);
            acc[1][n] = __builtin_amdgcn_mfma_f32_16x16x32_bf16(a1, bn, acc[1][n], 0, 0, 0);
        }
    }

    #pragma unroll
    for (int m = 0; m < 2; ++m) {
        #pragma unroll
        for (int rr = 0; rr < 4; ++rr) {
            float mx = -1e30f;
            #pragma unroll
            for (int n = 0; n < 16; ++n) mx = fmaxf(mx, acc[m][n][rr]);
            #pragma unroll
            for (int s = 1; s < 16; s <<= 1) mx = fmaxf(mx, __shfl_xor(mx, s));
            float sum = 0.0f;
            #pragma unroll
            for (int n = 0; n < 16; ++n) {
                float e = __expf(0.125f * (acc[m][n][rr] - mx));
                acc[m][n][rr] = e;
                sum += e;
            }
            #pragma unroll
            for (int s = 1; s < 16; s <<= 1) sum += __shfl_xor(sum, s);
            float inv = 1.0f / sum;
            int row = half * 128 + wave * 32 + m * 16 + g * 4 + rr;
            unsigned short* dst = probs + ((size_t)bh * Tz + row) * Tz;
            #pragma unroll
            for (int n = 0; n < 16; ++n) {
                float p = acc[m][n][rr] * inv;
                acc[m][n][rr] = p;
                dst[n * 16 + l15] = f2bf_rne(p);
            }
        }
    }
    __syncthreads();

    // --- phase 2: PV (64-key chunks) ---
    unsigned short* Vt = smem;                 // [64][VTPAD]
    unsigned short* Pl = smem + 64 * VTPAD;    // [128][PLPAD=72]
    const unsigned short* vbase = kp + (size_t)(b * Tz) * 512 + 256 + h * HDz;
    #pragma unroll
    for (int i = 0; i < 8; ++i) {
        int e = tid + i * 256;
        int key = e >> 3, c8 = e & 7;
        ushort8v v8 = *(const ushort8v*)(vbase + (size_t)key * 512 + c8 * 8);
        #pragma unroll
        for (int j = 0; j < 8; ++j)
            Vt[(c8 * 8 + j) * VTPAD + key] = v8[j];
    }

    f32x4 accpv[2][4] = {};
    for (int ks = 0; ks < 4; ++ks) {
        #pragma unroll
        for (int m = 0; m < 2; ++m) {
            #pragma unroll
            for (int rr = 0; rr < 4; ++rr) {
                int row = wave * 32 + m * 16 + g * 4 + rr;
                #pragma unroll
                for (int j = 0; j < 4; ++j)
                    Pl[row * PLPAD + j * 16 + l15] = f2bf_rne(acc[m][4 * ks + j][rr]);
            }
        }
        __syncthreads();
        #pragma unroll
        for (int kk = 0; kk < 2; ++kk) {
            short8v a0 = *(const short8v*)&Pl[(wave * 32 + l15) * PLPAD + kk * 32 + g * 8];
            short8v a1 = *(const short8v*)&Pl[(wave * 32 + 16 + l15) * PLPAD + kk * 32 + g * 8];
            #pragma unroll
            for (int n = 0; n < 4; ++n) {
                short8v bn = *(const short8v*)&Vt[(n * 16 + l15) * VTPAD + ks * 64 + kk * 32 + g * 8];
                accpv[0][n] = __builtin_amdgcn_mfma_f32_16x16x32_bf16(a0, bn, accpv[0][n], 0, 0, 0);
                accpv[1][n] = __builtin_amdgcn_mfma_f32_16x16x32_bf16(a1, bn, accpv[1][n], 0, 0, 0);
            }
        }
        __syncthreads();
    }

    #pragma unroll
    for (int m = 0; m < 2; ++m) {
        #pragma unroll
        for (int rr = 0; rr < 4; ++rr) {
            int row = b * Tz + half * 128 + wave * 32 + m * 16 + g * 4 + rr;
            #pragma unroll
            for (int n = 0; n < 4; ++n)
                pv[(size_t)row * Hz + h * HDz + n * 16 + l15] = f2bf_rne(accpv[m][n][rr]);
        }
    }
}

// combo4: meanheads(1024) | final(128)
__global__ __launch_bounds__(256) void combo4_kernel(
    const unsigned short* __restrict__ probs, float* __restrict__ out_attn,
    const unsigned short* __restrict__ qBF, const unsigned short* __restrict__ pvb,
    const unsigned short* __restrict__ WoutT, const unsigned short* __restrict__ WoWoutT,
    const float* __restrict__ bocomb, float* __restrict__ out_imputed)
{
    __shared__ unsigned short smem[5120];
    const int bid = blockIdx.x;
    const int tid = threadIdx.x;
    if (bid < 1024) {
        meanheads_body(probs, out_attn, bid, tid);
    } else {
        final_body(smem, qBF, pvb, WoutT, WoWoutT, bocomb, out_imputed, bid - 1024, tid);
    }
}

// ---------------------------------------------------------------------------
extern "C" void kernel_launch(void* const* d_in, const int* in_sizes, int n_in,
                              void* d_out, int out_size, void* d_ws, size_t ws_size,
                              hipStream_t stream)
{
    const float* batch_data = (const float*)d_in[0];
    const float* mask_probs = (const float*)d_in[1];
    const float* sapE       = (const float*)d_in[2];
    const float* pair_emb   = (const float*)d_in[3];
    const int*   pair_present = (const int*)d_in[4];
    const float* W_num = (const float*)d_in[5];  const float* b_num = (const float*)d_in[6];
    const float* W_sap = (const float*)d_in[7];  const float* b_sap = (const float*)d_in[8];
    const float* W_ad  = (const float*)d_in[9];  const float* b_ad  = (const float*)d_in[10];
    const float* Wq = (const float*)d_in[11]; const float* bq = (const float*)d_in[12];
    const float* Wk = (const float*)d_in[13]; const float* bk = (const float*)d_in[14];
    const float* Wv = (const float*)d_in[15]; const float* bv = (const float*)d_in[16];
    const float* Wo = (const float*)d_in[17]; const float* bo = (const float*)d_in[18];
    const float* W_out = (const float*)d_in[19]; const float* b_out = (const float*)d_in[20];

    float* out = (float*)d_out;
    float* out_imputed = out;                 // [B,T,F]
    float* out_stoch   = out + 524288;        // [B,T,F]
    float* out_attn    = out + 1048576;       // [B,T,T]

    float* ws = (float*)d_ws;
    unsigned short* safe_bf = (unsigned short*)ws;             // bf16 [8192][64]
    unsigned short* qBF   = (unsigned short*)(ws + 524288);    // bf16 [8192][256]
    unsigned short* probs = (unsigned short*)(ws + 2621440);   // bf16 [128][256][256]
    unsigned long long* sel = (unsigned long long*)(ws + 9961472); // u64 [8192][16]
    unsigned short* Pe    = (unsigned short*)(ws + 15204352);  // bf16 [1024][768] (dead after combo2)
    unsigned short* kvproj = (unsigned short*)(ws + 15204352); // bf16 [8192][512] (over dead Pe)
    unsigned short* pvb   = (unsigned short*)(ws + 17301504);  // bf16 [8192][256]
    unsigned short* WoWoutT = (unsigned short*)(ws + 18350080);// bf16 [64][256]
    float* bocomb = ws + 18358272;                             // 64 f32
    float* bkv    = ws + 18358336;                             // 512 f32
    float* inv_cnt = ws + 18358848;                            // 8192 f32
    unsigned short* WadkvT = (unsigned short*)(ws + 18367040); // bf16 [512][768]
    unsigned short* WadB   = (unsigned short*)(ws + 18563648); // bf16 [768][256]
    unsigned short* PeWaT  = (unsigned short*)(ws + 18661952); // bf16 [512][1024]
    float* pooled = ws + 19398656;
    unsigned long long* mask64 = (unsigned long long*)(ws + 19398912);
    unsigned int* plist = (unsigned int*)(ws + 19415296);

    unsigned short* wT = (unsigned short*)(ws + 19419392);
    unsigned short* WnumT = wT;                  // [256][64]
    unsigned short* WqT   = wT + 212992;         // [256][256]
    unsigned short* WkT   = wT + 278528;         // (WkT,WvT contiguous = WkvT)
    unsigned short* WvT   = wT + 344064;
    unsigned short* WoT   = wT + 409600;
    unsigned short* WoutT = wT + 475136;         // [64][256]

    // 1. prep (dead WadT removed)
    prep_kernel<<<401, 256, 0, stream>>>(
        Wk, Wv, Wo, W_out, W_ad, pair_present,
        WkT, WvT, WoT, WoutT, WadB, plist);
    // 2. combo1
    combo1_kernel<<<3185, 256, 0, stream>>>(
        WoutT, WoT, WoWoutT, WkT, WadB, WadkvT,
        sapE, W_sap, b_sap, pooled,
        batch_data, mask_probs, safe_bf, out_stoch, mask64,
        pair_emb, plist, Pe,
        W_num, WnumT, Wq, WqT, bo, b_out, W_out, bocomb,
        b_ad, bk, bv, Wk, Wv, bkv);
    // 3. combo2: query GEMM | wbuild | PeWaT
    combo2_kernel<<<672, 256, 0, stream>>>(
        safe_bf, WnumT, b_num, pooled, qBF,
        mask64, plist, sel, inv_cnt, WadkvT, Pe, PeWaT);
    // 4. combo3: selkv only
    combo3_kernel<<<512, 256, 0, stream>>>(
        sel, PeWaT, inv_cnt, bkv, kvproj);
    // 5. fused attention (+ in-kernel q projection)
    attn_fused_kernel<<<256, 256, 0, stream>>>(qBF, WqT, bq, kvproj, probs, pvb);
    // 6. combo4: meanheads | final
    combo4_kernel<<<1152, 256, 0, stream>>>(
        probs, out_attn, qBF, pvb, WoutT, WoWoutT, bocomb, out_imputed);
}

// Round 15
// 115.355 us; speedup vs baseline: 1.3114x; 1.0369x over previous
//
#include <hip/hip_runtime.h>
#include <hip/hip_bf16.h>

// Shapes
#define Bz 32
#define Tz 256
#define Fz 64
#define Dz 768
#define Sz 768
#define Hz 256
#define NHz 4
#define HDz 64
#define BTz 8192  // B*T
#define NPAIRPAD 1024
#define QKPAD 72   // bf16 units; 144B row stride: 2-way bank alias (free)
#define VTPAD 264
#define PLPAD 72   // PV 64-key chunk

typedef __attribute__((ext_vector_type(8))) short short8v;
typedef __attribute__((ext_vector_type(8))) unsigned short ushort8v;
typedef __attribute__((ext_vector_type(4))) float f32x4;

__device__ inline unsigned short f2bf_rne(float x) {
    unsigned u = __float_as_uint(x);
    unsigned r = (u + 0x7fffu + ((u >> 16) & 1u)) >> 16;
    return (unsigned short)r;
}
__device__ inline float bf2f(unsigned short x) {
    return __uint_as_float(((unsigned)x) << 16);
}
__device__ inline short8v expand8(unsigned bits) {
    short8v r;
    #pragma unroll
    for (int j = 0; j < 8; ++j)
        r[j] = (bits & (1u << j)) ? (short)0x3f80 : (short)0;
    return r;
}

// ===========================================================================
// Device bodies
// ===========================================================================

// Unified LDS-staged MFMA GEMM body.
template <int BM, int BN, bool OUTBF16, int B2MODE>
__device__ __forceinline__ void gemm2_body(
    unsigned short* __restrict__ smem,
    const unsigned short* __restrict__ A,
    const unsigned short* __restrict__ Bt,
    const float* __restrict__ bias, const float* __restrict__ bias2,
    void* __restrict__ Cv, int M, int N, int K, int bx, int by, int tid)
{
    constexpr int WC = BN / 64;
    constexpr int WR = 4 / WC;
    constexpr int RW = BM / WR;
    constexpr int MT = RW / 16;
    constexpr int NT = 4;
    unsigned short* As = smem;
    unsigned short* Bs = smem + BM * 40;
    const int lane = tid & 63, wave = tid >> 6;
    const int l15 = lane & 15, g = lane >> 4;
    const int wr = wave / WC, wc = wave % WC;
    const int row0 = by * BM, col0 = bx * BN;

    f32x4 acc[MT][NT] = {};

    for (int k0 = 0; k0 < K; k0 += 32) {
        __syncthreads();
        #pragma unroll
        for (int i = 0; i < BM * 4 / 256; ++i) {
            int e = tid + i * 256;
            int r = e >> 2, c8 = e & 3;
            *(ushort8v*)(As + r * 40 + c8 * 8) =
                *(const ushort8v*)(A + (size_t)(row0 + r) * K + k0 + c8 * 8);
        }
        #pragma unroll
        for (int i = 0; i < BN * 4 / 256; ++i) {
            int e = tid + i * 256;
            int n = e >> 2, c = e & 3;
            *(ushort8v*)(Bs + n * 40 + c * 8) =
                *(const ushort8v*)(Bt + (size_t)(col0 + n) * K + k0 + c * 8);
        }
        __syncthreads();

        short8v a[MT], b[NT];
        #pragma unroll
        for (int m = 0; m < MT; ++m)
            a[m] = *(const short8v*)(As + (wr * RW + m * 16 + l15) * 40 + g * 8);
        #pragma unroll
        for (int n = 0; n < NT; ++n)
            b[n] = *(const short8v*)(Bs + (wc * 64 + n * 16 + l15) * 40 + g * 8);
        #pragma unroll
        for (int m = 0; m < MT; ++m)
            #pragma unroll
            for (int n = 0; n < NT; ++n)
                acc[m][n] = __builtin_amdgcn_mfma_f32_16x16x32_bf16(a[m], b[n], acc[m][n], 0, 0, 0);
    }

    #pragma unroll
    for (int m = 0; m < MT; ++m) {
        #pragma unroll
        for (int rr = 0; rr < 4; ++rr) {
            int row = row0 + wr * RW + m * 16 + g * 4 + rr;
            #pragma unroll
            for (int n = 0; n < NT; ++n) {
                int col = col0 + wc * 64 + n * 16 + l15;
                float o = acc[m][n][rr];
                if (B2MODE == 2) {
                    o += (col < (N >> 1)) ? bias[col] : bias2[col - (N >> 1)];
                } else if (B2MODE != 3) {
                    o += bias[col];
                    if (B2MODE == 1) o += bias2[col];
                }
                if (OUTBF16) ((unsigned short*)Cv)[(size_t)row * N + col] = f2bf_rne(o);
                else         ((float*)Cv)[(size_t)row * N + col] = o;
            }
        }
    }
}

// selkv hybrid GEMM (R13-proven): A from sel bits in regs, B chunked+swizzled LDS.
__device__ __forceinline__ void gemm_selkv_body2(
    unsigned short* __restrict__ smem,         // >= 128*128 ushorts (32 KB)
    const unsigned long long* __restrict__ sel,
    const unsigned short* __restrict__ Bt,     // PeWaT [512][1024]
    const float* __restrict__ rs,              // inv_cnt [8192]
    const float* __restrict__ bias,            // bkv [512]
    unsigned short* __restrict__ C,            // kvproj [8192][512]
    int bx, int by, int tid)
{
    unsigned short* Bs = smem;
    const int lane = tid & 63, wave = tid >> 6;
    const int l15 = lane & 15, g = lane >> 4;
    const int wr = wave >> 1, wc = wave & 1;
    const int row0 = by * 64, col0 = bx * 128;

    const unsigned long long* selr0 = sel + (size_t)(row0 + wr * 32 + l15) * 16;
    const unsigned long long* selr1 = selr0 + 16 * 16;

    f32x4 acc[2][4] = {};

    for (int kc = 0; kc < 1024; kc += 128) {
        __syncthreads();
        #pragma unroll
        for (int i = 0; i < 8; ++i) {
            int e = tid + i * 256;
            int r = e >> 4, c8 = e & 15;
            int slot = c8 ^ (r & 7);
            *(ushort8v*)(Bs + r * 128 + slot * 8) =
                *(const ushort8v*)(Bt + (size_t)(col0 + r) * 1024 + kc + c8 * 8);
        }
        __syncthreads();

        #pragma unroll
        for (int kk = 0; kk < 4; ++kk) {
            const int k0 = kc + kk * 32;
            const int word = k0 >> 6;
            const int shift = (k0 & 32) + g * 8;
            short8v a0 = expand8((unsigned)(selr0[word] >> shift) & 0xFFu);
            short8v a1 = expand8((unsigned)(selr1[word] >> shift) & 0xFFu);
            #pragma unroll
            for (int n = 0; n < 4; ++n) {
                int row = wc * 64 + n * 16 + l15;
                int slot = (kk * 4 + g) ^ (row & 7);
                short8v bn = *(const short8v*)(Bs + row * 128 + slot * 8);
                acc[0][n] = __builtin_amdgcn_mfma_f32_16x16x32_bf16(a0, bn, acc[0][n], 0, 0, 0);
                acc[1][n] = __builtin_amdgcn_mfma_f32_16x16x32_bf16(a1, bn, acc[1][n], 0, 0, 0);
            }
        }
    }

    #pragma unroll
    for (int m = 0; m < 2; ++m) {
        #pragma unroll
        for (int rr = 0; rr < 4; ++rr) {
            int row = row0 + wr * 32 + m * 16 + g * 4 + rr;
            float s = rs[row];
            #pragma unroll
            for (int n = 0; n < 4; ++n) {
                int col = col0 + wc * 64 + n * 16 + l15;
                C[(size_t)row * 512 + col] = f2bf_rne(acc[m][n][rr] * s + bias[col]);
            }
        }
    }
}

// masking body
__device__ __forceinline__ void mask_body(
    const float* __restrict__ bd, const float* __restrict__ mp,
    unsigned short* __restrict__ safe_bf, float* __restrict__ stoch_out,
    unsigned long long* __restrict__ mask64, int bid, int tid)
{
    int idx = bid * 256 + tid;
    float x = bd[idx];
    float p = mp[idx];
    unsigned xb = __float_as_uint(x);
    bool valid = ((xb & 0x7fffffffu) <= 0x7f800000u);
    bool st = (p < 0.3f) && valid;
    bool sv = valid && !st;
    safe_bf[idx] = sv ? f2bf_rne(x) : 0;
    stoch_out[idx] = st ? 1.0f : 0.0f;
    unsigned long long m = __ballot(sv);
    if ((tid & 63) == 0) mask64[idx >> 6] = m;
}

// pooled body
__device__ __forceinline__ void pooled_body(
    unsigned short* __restrict__ smem,
    const float* __restrict__ E, const float* __restrict__ W_sap,
    const float* __restrict__ b_sap, float* __restrict__ pooled, int bid, int tid)
{
    float* colmean = (float*)smem;
    float* red = colmean + Sz;
    for (int s = tid; s < Sz; s += 256) {
        float a = 0.0f;
        #pragma unroll 8
        for (int f = 0; f < Fz; ++f) a += E[(size_t)f * Sz + s];
        colmean[s] = a * (1.0f / 64.0f);
    }
    __syncthreads();
    const int hl = tid & 63, sg = tid >> 6;
    const int h = bid * 64 + hl;
    float acc = 0.0f;
    #pragma unroll 4
    for (int s = sg; s < Sz; s += 4)
        acc = fmaf(colmean[s], W_sap[(size_t)s * Hz + h], acc);
    red[sg * 64 + hl] = acc;
    __syncthreads();
    if (sg == 0)
        pooled[h] = b_sap[h] + ((red[hl] + red[64 + hl]) + (red[128 + hl] + red[192 + hl]));
}

// wbuild body
__device__ __forceinline__ void wbuild_body(
    unsigned short* __restrict__ smem,
    const unsigned long long* __restrict__ mask64,
    const unsigned int* __restrict__ plist,
    unsigned long long* __restrict__ sel, float* __restrict__ inv_cnt,
    int bid, int tid)
{
    unsigned int* pl = (unsigned int*)smem;
    for (int i = tid; i < NPAIRPAD; i += 256) pl[i] = plist[1 + i];
    __syncthreads();
    const int np = (int)plist[0];
    const int btl = tid >> 4, w = tid & 15;
    const int bt = bid * 16 + btl;
    unsigned long long m = mask64[bt];
    unsigned long long word = 0ull;
    int pbase = w * 64;
    int jmax = min(64, np - pbase);
    for (int j = 0; j < jmax; ++j) {
        unsigned ij = pl[pbase + j];
        unsigned long long bit = (m >> (ij >> 6)) & (m >> (ij & 63)) & 1ull;
        word |= bit << j;
    }
    sel[(size_t)bt * 16 + w] = word;
    int c = __popcll(word);
    #pragma unroll
    for (int s = 1; s < 16; s <<= 1) c += __shfl_xor(c, s);
    if (w == 0) inv_cnt[bt] = c > 0 ? 1.0f / (float)c : 0.0f;
}

// pe body
__device__ __forceinline__ void pe_body(
    const float* __restrict__ pair_emb, const unsigned int* __restrict__ plist,
    unsigned short* __restrict__ Pe, int p, int t)
{
    int np = (int)plist[0];
    if (p < np) {
        unsigned ij = plist[1 + p];
        const float* src = pair_emb + (size_t)ij * Dz;
        #pragma unroll
        for (int c = 0; c < 3; ++c)
            Pe[(size_t)p * Dz + t + c * 256] = f2bf_rne(src[t + c * 256]);
    } else {
        #pragma unroll
        for (int c = 0; c < 3; ++c)
            Pe[(size_t)p * Dz + t + c * 256] = 0;
    }
}

// meanheads body
__device__ __forceinline__ void meanheads_body(
    const unsigned short* __restrict__ probs, float* __restrict__ out3,
    int bid, int tid)
{
    int idx = bid * 256 + tid;
    int tk8 = idx & 31;
    int btq = idx >> 5;
    int b = btq >> 8, tq = btq & 255;
    float acc[8] = {};
    #pragma unroll
    for (int h = 0; h < 4; ++h) {
        int bh = b * 4 + h;
        ushort8v p = *(const ushort8v*)&probs[(((size_t)bh * Tz + tq) << 8) + tk8 * 8];
        #pragma unroll
        for (int j = 0; j < 8; ++j) acc[j] += bf2f(p[j]) * 0.25f;
    }
    float* dst = out3 + ((size_t)btq << 8) + tk8 * 8;
    float4 o0 = {acc[0], acc[1], acc[2], acc[3]};
    float4 o1 = {acc[4], acc[5], acc[6], acc[7]};
    *(float4*)dst = o0;
    *(float4*)(dst + 4) = o1;
}

// final body: out = safe @ WnWoT^T (K=64) + pvb @ WoWoutT^T (K=256) + bfin.
__device__ __forceinline__ void final_body(
    unsigned short* __restrict__ smem,
    const unsigned short* __restrict__ safe_bf, const unsigned short* __restrict__ pvb,
    const unsigned short* __restrict__ WnWoT, const unsigned short* __restrict__ WWT,
    const float* __restrict__ bias, float* __restrict__ C, int bid, int tid)
{
    unsigned short* As = smem;
    unsigned short* Bs = smem + 64 * 40;
    const int lane = tid & 63, wave = tid >> 6;
    const int l15 = lane & 15, g = lane >> 4;
    const int row0 = bid * 64;

    f32x4 acc[4] = {};

    // phase 1: safe [64 rows][64 k] @ WnWoT [64][64]
    for (int k0 = 0; k0 < 64; k0 += 32) {
        __syncthreads();
        {
            int r = tid >> 2, c8 = tid & 3;
            *(ushort8v*)(As + r * 40 + c8 * 8) =
                *(const ushort8v*)(safe_bf + (size_t)(row0 + r) * Fz + k0 + c8 * 8);
            *(ushort8v*)(Bs + r * 40 + c8 * 8) =
                *(const ushort8v*)(WnWoT + (size_t)r * Fz + k0 + c8 * 8);
        }
        __syncthreads();
        short8v a = *(const short8v*)(As + (wave * 16 + l15) * 40 + g * 8);
        #pragma unroll
        for (int n = 0; n < 4; ++n) {
            short8v bn = *(const short8v*)(Bs + (n * 16 + l15) * 40 + g * 8);
            acc[n] = __builtin_amdgcn_mfma_f32_16x16x32_bf16(a, bn, acc[n], 0, 0, 0);
        }
    }
    // phase 2: pvb [64 rows][256 k] @ WoWoutT [64][256]
    for (int k0 = 0; k0 < 256; k0 += 32) {
        __syncthreads();
        {
            int r = tid >> 2, c8 = tid & 3;
            *(ushort8v*)(As + r * 40 + c8 * 8) =
                *(const ushort8v*)(pvb + (size_t)(row0 + r) * Hz + k0 + c8 * 8);
            *(ushort8v*)(Bs + r * 40 + c8 * 8) =
                *(const ushort8v*)(WWT + (size_t)r * Hz + k0 + c8 * 8);
        }
        __syncthreads();
        short8v a = *(const short8v*)(As + (wave * 16 + l15) * 40 + g * 8);
        #pragma unroll
        for (int n = 0; n < 4; ++n) {
            short8v bn = *(const short8v*)(Bs + (n * 16 + l15) * 40 + g * 8);
            acc[n] = __builtin_amdgcn_mfma_f32_16x16x32_bf16(a, bn, acc[n], 0, 0, 0);
        }
    }

    #pragma unroll
    for (int rr = 0; rr < 4; ++rr) {
        int row = row0 + wave * 16 + g * 4 + rr;
        #pragma unroll
        for (int n = 0; n < 4; ++n) {
            int col = n * 16 + l15;
            C[(size_t)row * Fz + col] = acc[n][rr] + bias[col];
        }
    }
}

// ===========================================================================
// Kernels
// ===========================================================================

__device__ inline void transpose_tile2(const float* __restrict__ in,
                                       unsigned short* __restrict__ out,
                                       int R, int C, int bx, int by, int tid)
{
    __shared__ float t[32][33];
    const int c0 = bx * 32, r0 = by * 32;
    const int lc = tid & 31, lr8 = tid >> 5;
    #pragma unroll
    for (int i = 0; i < 4; ++i) {
        int r = lr8 + i * 8;
        t[r][lc] = in[(size_t)(r0 + r) * C + c0 + lc];
    }
    __syncthreads();
    #pragma unroll
    for (int i = 0; i < 4; ++i) {
        int oc = lr8 + i * 8;
        out[(size_t)(c0 + oc) * R + r0 + lc] = f2bf_rne(t[lc][oc]);
    }
}

// prep: WkT(64) | WvT(64) | WoT(64) | WoutT(16) | WadB(192) | WqT(64)
//     | WnumB(16) | plist(1) = 481
__global__ __launch_bounds__(256) void prep_kernel(
    const float* __restrict__ Wk, const float* __restrict__ Wv,
    const float* __restrict__ Wo, const float* __restrict__ W_out,
    const float* __restrict__ W_ad, const float* __restrict__ Wq,
    const float* __restrict__ W_num, const int* __restrict__ present,
    unsigned short* __restrict__ WkT, unsigned short* __restrict__ WvT,
    unsigned short* __restrict__ WoT, unsigned short* __restrict__ WoutT,
    unsigned short* __restrict__ WadB, unsigned short* __restrict__ WqT,
    unsigned short* __restrict__ WnumB, unsigned int* __restrict__ plist)
{
    const int bid = blockIdx.x;
    const int tid = threadIdx.x;
    if (bid < 64) {
        transpose_tile2(Wk, WkT, Hz, Hz, bid & 7, bid >> 3, tid);
    } else if (bid < 128) {
        int lid = bid - 64;
        transpose_tile2(Wv, WvT, Hz, Hz, lid & 7, lid >> 3, tid);
    } else if (bid < 192) {
        int lid = bid - 128;
        transpose_tile2(Wo, WoT, Hz, Hz, lid & 7, lid >> 3, tid);
    } else if (bid < 208) {
        int lid = bid - 192;
        transpose_tile2(W_out, WoutT, Hz, Fz, lid & 1, lid >> 1, tid);
    } else if (bid < 400) {               // WadB bf16 copy (192 blocks)
        int lid = bid - 208;
        int base = lid * 1024 + tid * 4;
        #pragma unroll
        for (int j = 0; j < 4; ++j) WadB[base + j] = f2bf_rne(W_ad[base + j]);
    } else if (bid < 464) {               // WqT
        int lid = bid - 400;
        transpose_tile2(Wq, WqT, Hz, Hz, lid & 7, lid >> 3, tid);
    } else if (bid < 480) {               // WnumB bf16 copy (16 blocks x 1024)
        int lid = bid - 464;
        int base = lid * 1024 + tid * 4;
        #pragma unroll
        for (int j = 0; j < 4; ++j) WnumB[base + j] = f2bf_rne(W_num[base + j]);
    } else {                              // pairlist
        __shared__ int cnt[64];
        __shared__ int off[64];
        int i = tid;
        if (i < 64) {
            int c = 0;
            for (int j = i + 1; j < 64; ++j)
                if (present[i * 64 + j] != 0) c++;
            cnt[i] = c;
        }
        __syncthreads();
        if (i == 0) {
            int t = 0;
            for (int r = 0; r < 64; ++r) { off[r] = t; t += cnt[r]; }
            plist[0] = (unsigned)t;
        }
        __syncthreads();
        if (i < 64) {
            int o = 1 + off[i];
            for (int j = i + 1; j < 64; ++j)
                if (present[i * 64 + j] != 0) plist[o++] = (unsigned)(i * 64 + j);
        }
    }
}

// combo1: WoWoutT(2) | WadkvT(24) | WnumWqT(2) | WnWoT(1) | pooled(4)
//       | mask(2048) | pe(1024) | bocomb(1) | bkv(2) = 3108 blocks
__global__ __launch_bounds__(256) void combo1_kernel(
    const unsigned short* __restrict__ WoutT, const unsigned short* __restrict__ WoT,
    unsigned short* __restrict__ WoWoutT,
    const unsigned short* __restrict__ WkT, const unsigned short* __restrict__ WadB,
    unsigned short* __restrict__ WadkvT,
    const unsigned short* __restrict__ WqT, const unsigned short* __restrict__ WnumB,
    unsigned short* __restrict__ WnumWqT, unsigned short* __restrict__ WnWoT,
    const float* __restrict__ sapE, const float* __restrict__ W_sap,
    const float* __restrict__ b_sap, float* __restrict__ pooled,
    const float* __restrict__ batch_data, const float* __restrict__ mask_probs,
    unsigned short* __restrict__ safe_bf, float* __restrict__ stoch_out,
    unsigned long long* __restrict__ mask64,
    const float* __restrict__ pair_emb, const unsigned int* __restrict__ plist,
    unsigned short* __restrict__ Pe,
    const float* __restrict__ bo, const float* __restrict__ b_out,
    const float* __restrict__ W_out, float* __restrict__ bocomb,
    const float* __restrict__ b_ad, const float* __restrict__ bk,
    const float* __restrict__ bv, const float* __restrict__ Wk,
    const float* __restrict__ Wv, float* __restrict__ bkv)
{
    __shared__ unsigned short smem[10240];   // 20 KB
    const int bid = blockIdx.x;
    const int tid = threadIdx.x;
    if (bid < 2) {
        gemm2_body<64, 128, true, 3>(smem, WoutT, WoT, nullptr, nullptr,
                                     WoWoutT, 64, Hz, Hz, bid, 0, tid);
    } else if (bid < 26) {
        int lid = bid - 2;
        gemm2_body<128, 128, true, 3>(smem, WkT, WadB, nullptr, nullptr,
                                      WadkvT, 512, Dz, Hz, lid % 6, lid / 6, tid);
    } else if (bid < 28) {
        // WnumWqT[256][64] = WqT[256][256] @ WnumB[64][256]^T
        gemm2_body<128, 64, true, 3>(smem, WqT, WnumB, nullptr, nullptr,
                                     WnumWqT, Hz, Fz, Hz, 0, bid - 26, tid);
    } else if (bid == 28) {
        // WnWoT[64][64] = WoutT[64][256] @ WnumB[64][256]^T
        gemm2_body<64, 64, true, 3>(smem, WoutT, WnumB, nullptr, nullptr,
                                    WnWoT, Fz, Fz, Hz, 0, 0, tid);
    } else if (bid < 33) {
        pooled_body(smem, sapE, W_sap, b_sap, pooled, bid - 29, tid);
    } else if (bid < 2081) {
        mask_body(batch_data, mask_probs, safe_bf, stoch_out, mask64, bid - 33, tid);
    } else if (bid < 3105) {
        pe_body(pair_emb, plist, Pe, bid - 2081, tid);
    } else if (bid == 3105) {             // bocomb
        int c = tid;
        if (c < 64) {
            float a = b_out[c];
            for (int j = 0; j < 256; ++j) a = fmaf(bo[j], W_out[(size_t)j * 64 + c], a);
            bocomb[c] = a;
        }
    } else {                              // bkv (2 blocks)
        int c = tid;
        const float* Wx = (bid == 3106) ? Wk : Wv;
        const float* bx = (bid == 3106) ? bk : bv;
        float a = bx[c];
        for (int j = 0; j < 256; ++j) a = fmaf(b_ad[j], Wx[(size_t)j * Hz + c], a);
        bkv[(bid - 3106) * 256 + c] = a;
    }
}

// combo2: wbuild(512) | PeWaT GEMM(32) | bnq(1) | bfin(1) = 546
__global__ __launch_bounds__(256) void combo2_kernel(
    const unsigned long long* __restrict__ mask64, const unsigned int* __restrict__ plist,
    unsigned long long* __restrict__ sel, float* __restrict__ inv_cnt,
    const unsigned short* __restrict__ WadkvT, const unsigned short* __restrict__ Pe,
    unsigned short* __restrict__ PeWaT,
    const float* __restrict__ b_num, const float* __restrict__ pooled,
    const float* __restrict__ Wq, const float* __restrict__ bq,
    float* __restrict__ bnq,
    const float* __restrict__ W_out, const float* __restrict__ bocomb,
    float* __restrict__ bfin)
{
    __shared__ unsigned short smem[10240];
    const int bid = blockIdx.x;
    const int tid = threadIdx.x;
    if (bid < 512) {
        wbuild_body(smem, mask64, plist, sel, inv_cnt, bid, tid);
    } else if (bid < 544) {
        int lid = bid - 512;
        gemm2_body<128, 128, true, 3>(smem, WadkvT, Pe, nullptr, nullptr,
                                      PeWaT, 512, NPAIRPAD, Dz, lid & 7, lid >> 3, tid);
    } else if (bid == 544) {              // bnq[256] = (b_num+pooled)@Wq + bq
        int c = tid;
        float a = bq[c];
        for (int j = 0; j < 256; ++j)
            a = fmaf(b_num[j] + pooled[j], Wq[(size_t)j * Hz + c], a);
        bnq[c] = a;
    } else {                              // bfin[64] = bocomb + (b_num+pooled)@W_out
        int c = tid;
        if (c < 64) {
            float a = bocomb[c];
            for (int j = 0; j < 256; ++j)
                a = fmaf(b_num[j] + pooled[j], W_out[(size_t)j * 64 + c], a);
            bfin[c] = a;
        }
    }
}

// combo3: selkv hybrid GEMM only (512 blocks)
__global__ __launch_bounds__(256) void combo3_kernel(
    const unsigned long long* __restrict__ sel, const unsigned short* __restrict__ PeWaT,
    const float* __restrict__ inv_cnt, const float* __restrict__ bkv,
    unsigned short* __restrict__ kvproj)
{
    __shared__ unsigned short smem[16384];   // 32 KB
    gemm_selkv_body2(smem, sel, PeWaT, inv_cnt, bkv, kvproj,
                     blockIdx.x & 3, blockIdx.x >> 2, threadIdx.x);
}

// Fused attention with in-kernel Q projection (K=64 from safe):
// Q_h = safe @ WnumWqT_h + bnq_h  (single LDS chunk) -> Ql; QK^T/softmax/PV.
__global__ __launch_bounds__(256) void attn_fused_kernel(
    const unsigned short* __restrict__ safe_bf, const unsigned short* __restrict__ WnumWqT,
    const float* __restrict__ bnq, const unsigned short* __restrict__ kp,
    unsigned short* __restrict__ probs, unsigned short* __restrict__ pv)
{
    int blk = blockIdx.x;
    int bh = blk >> 1, half = blk & 1;
    int b = bh >> 2, h = bh & 3;
    __shared__ unsigned short smem[128 * QKPAD + 256 * QKPAD];  // 55296 B
    unsigned short* Ql = smem;                 // [128][QKPAD]
    unsigned short* Kl = smem + 128 * QKPAD;   // [256][QKPAD]
    unsigned short* Aq = smem;                 // qproj A [128][QKPAD] (over Ql)
    unsigned short* Bq = smem + 128 * QKPAD;   // qproj B [64][QKPAD] (over Kl)
    const int tid = threadIdx.x;
    const int lane = tid & 63, wave = tid >> 6;
    const int l15 = lane & 15, g = lane >> 4;

    // --- phase 0: Q projection (K=64) ---
    {
        const unsigned short* abase = safe_bf + (size_t)(b * Tz + half * 128) * Fz;
        #pragma unroll
        for (int i = 0; i < 4; ++i) {        // 128 rows x 8 vec8
            int e = tid + i * 256;
            int r = e >> 3, k8 = e & 7;
            *(ushort8v*)(Aq + r * QKPAD + k8 * 8) =
                *(const ushort8v*)(abase + (size_t)r * Fz + k8 * 8);
        }
        const unsigned short* src = WnumWqT + (size_t)(h * 64) * Fz;
        #pragma unroll
        for (int i = 0; i < 2; ++i) {        // 64 rows x 8 vec8
            int e = tid + i * 256;
            int n = e >> 3, k8 = e & 7;
            *(ushort8v*)(Bq + n * QKPAD + k8 * 8) =
                *(const ushort8v*)(src + (size_t)n * Fz + k8 * 8);
        }
    }
    __syncthreads();
    f32x4 acc_q[2][4] = {};
    #pragma unroll
    for (int kk = 0; kk < 2; ++kk) {
        short8v a0 = *(const short8v*)(Aq + (wave * 32 + l15) * QKPAD + kk * 32 + g * 8);
        short8v a1 = *(const short8v*)(Aq + (wave * 32 + 16 + l15) * QKPAD + kk * 32 + g * 8);
        #pragma unroll
        for (int n = 0; n < 4; ++n) {
            short8v bn = *(const short8v*)(Bq + (n * 16 + l15) * QKPAD + kk * 32 + g * 8);
            acc_q[0][n] = __builtin_amdgcn_mfma_f32_16x16x32_bf16(a0, bn, acc_q[0][n], 0, 0, 0);
            acc_q[1][n] = __builtin_amdgcn_mfma_f32_16x16x32_bf16(a1, bn, acc_q[1][n], 0, 0, 0);
        }
    }
    __syncthreads();   // all Aq/Bq reads done

    // write Q (+bias, cvt bf16) into Ql; stage K into Kl
    #pragma unroll
    for (int m = 0; m < 2; ++m) {
        #pragma unroll
        for (int rr = 0; rr < 4; ++rr) {
            int row = wave * 32 + m * 16 + g * 4 + rr;
            #pragma unroll
            for (int n = 0; n < 4; ++n) {
                int col = n * 16 + l15;
                Ql[row * QKPAD + col] = f2bf_rne(acc_q[m][n][rr] + bnq[h * 64 + col]);
            }
        }
    }
    const unsigned short* kbase = kp + (size_t)(b * Tz) * 512 + h * HDz;
    #pragma unroll
    for (int i = 0; i < 8; ++i) {
        int e = tid + i * 256;
        int r = e >> 3, c8 = e & 7;
        *(ushort8v*)&Kl[r * QKPAD + c8 * 8] =
            *(const ushort8v*)(kbase + (size_t)r * 512 + c8 * 8);
    }
    __syncthreads();

    // --- phase 1: QK^T + softmax ---
    f32x4 acc[2][16] = {};
    #pragma unroll
    for (int ks = 0; ks < 2; ++ks) {
        short8v a0 = *(const short8v*)&Ql[(wave * 32 + l15) * QKPAD + ks * 32 + g * 8];
        short8v a1 = *(const short8v*)&Ql[(wave * 32 + 16 + l15) * QKPAD + ks * 32 + g * 8];
        #pragma unroll
        for (int n = 0; n < 16; ++n) {
            short8v bn = *(const short8v*)&Kl[(n * 16 + l15) * QKPAD + ks * 32 + g * 8];
            acc[0][n] = __builtin_amdgcn_mfma_f32_16x16x32_bf16(a0, bn, acc[0][n], 0, 0, 0);
            acc[1][n] = __builtin_amdgcn_mfma_f32_16x16x32_bf16(a1, bn, acc[1][n], 0, 0, 0);
        }
    }

    #pragma unroll
    for (int m = 0; m < 2; ++m) {
        #pragma unroll
        for (int rr = 0; rr < 4; ++rr) {
            float mx = -1e30f;
            #pragma unroll
            for (int n = 0; n < 16; ++n) mx = fmaxf(mx, acc[m][n][rr]);
            #pragma unroll
            for (int s = 1; s < 16; s <<= 1) mx = fmaxf(mx, __shfl_xor(mx, s));
            float sum = 0.0f;
            #pragma unroll
            for (int n = 0; n < 16; ++n) {
                float e = __expf(0.125f * (acc[m][n][rr] - mx));
                acc[m][n][rr] = e;
                sum += e;
            }
            #pragma unroll
            for (int s = 1; s < 16; s <<= 1) sum += __shfl_xor(sum, s);
            float inv = 1.0f / sum;
            int row = half * 128 + wave * 32 + m * 16 + g * 4 + rr;
            unsigned short* dst = probs + ((size_t)bh * Tz + row) * Tz;
            #pragma unroll
            for (int n = 0; n < 16; ++n) {
                float p = acc[m][n][rr] * inv;
                acc[m][n][rr] = p;
                dst[n * 16 + l15] = f2bf_rne(p);
            }
        }
    }
    __syncthreads();

    // --- phase 2: PV (64-key chunks) ---
    unsigned short* Vt = smem;                 // [64][VTPAD]
    unsigned short* Pl = smem + 64 * VTPAD;    // [128][PLPAD=72]
    const unsigned short* vbase = kp + (size_t)(b * Tz) * 512 + 256 + h * HDz;
    #pragma unroll
    for (int i = 0; i < 8; ++i) {
        int e = tid + i * 256;
        int key = e >> 3, c8 = e & 7;
        ushort8v v8 = *(const ushort8v*)(vbase + (size_t)key * 512 + c8 * 8);
        #pragma unroll
        for (int j = 0; j < 8; ++j)
            Vt[(c8 * 8 + j) * VTPAD + key] = v8[j];
    }

    f32x4 accpv[2][4] = {};
    for (int ks = 0; ks < 4; ++ks) {
        #pragma unroll
        for (int m = 0; m < 2; ++m) {
            #pragma unroll
            for (int rr = 0; rr < 4; ++rr) {
                int row = wave * 32 + m * 16 + g * 4 + rr;
                #pragma unroll
                for (int j = 0; j < 4; ++j)
                    Pl[row * PLPAD + j * 16 + l15] = f2bf_rne(acc[m][4 * ks + j][rr]);
            }
        }
        __syncthreads();
        #pragma unroll
        for (int kk = 0; kk < 2; ++kk) {
            short8v a0 = *(const short8v*)&Pl[(wave * 32 + l15) * PLPAD + kk * 32 + g * 8];
            short8v a1 = *(const short8v*)&Pl[(wave * 32 + 16 + l15) * PLPAD + kk * 32 + g * 8];
            #pragma unroll
            for (int n = 0; n < 4; ++n) {
                short8v bn = *(const short8v*)&Vt[(n * 16 + l15) * VTPAD + ks * 64 + kk * 32 + g * 8];
                accpv[0][n] = __builtin_amdgcn_mfma_f32_16x16x32_bf16(a0, bn, accpv[0][n], 0, 0, 0);
                accpv[1][n] = __builtin_amdgcn_mfma_f32_16x16x32_bf16(a1, bn, accpv[1][n], 0, 0, 0);
            }
        }
        __syncthreads();
    }

    #pragma unroll
    for (int m = 0; m < 2; ++m) {
        #pragma unroll
        for (int rr = 0; rr < 4; ++rr) {
            int row = b * Tz + half * 128 + wave * 32 + m * 16 + g * 4 + rr;
            #pragma unroll
            for (int n = 0; n < 4; ++n)
                pv[(size_t)row * Hz + h * HDz + n * 16 + l15] = f2bf_rne(accpv[m][n][rr]);
        }
    }
}

// combo4: meanheads(1024) | final(128)
__global__ __launch_bounds__(256) void combo4_kernel(
    const unsigned short* __restrict__ probs, float* __restrict__ out_attn,
    const unsigned short* __restrict__ safe_bf, const unsigned short* __restrict__ pvb,
    const unsigned short* __restrict__ WnWoT, const unsigned short* __restrict__ WoWoutT,
    const float* __restrict__ bfin, float* __restrict__ out_imputed)
{
    __shared__ unsigned short smem[5120];
    const int bid = blockIdx.x;
    const int tid = threadIdx.x;
    if (bid < 1024) {
        meanheads_body(probs, out_attn, bid, tid);
    } else {
        final_body(smem, safe_bf, pvb, WnWoT, WoWoutT, bfin, out_imputed, bid - 1024, tid);
    }
}

// ---------------------------------------------------------------------------
extern "C" void kernel_launch(void* const* d_in, const int* in_sizes, int n_in,
                              void* d_out, int out_size, void* d_ws, size_t ws_size,
                              hipStream_t stream)
{
    const float* batch_data = (const float*)d_in[0];
    const float* mask_probs = (const float*)d_in[1];
    const float* sapE       = (const float*)d_in[2];
    const float* pair_emb   = (const float*)d_in[3];
    const int*   pair_present = (const int*)d_in[4];
    const float* W_num = (const float*)d_in[5];  const float* b_num = (const float*)d_in[6];
    const float* W_sap = (const float*)d_in[7];  const float* b_sap = (const float*)d_in[8];
    const float* W_ad  = (const float*)d_in[9];  const float* b_ad  = (const float*)d_in[10];
    const float* Wq = (const float*)d_in[11]; const float* bq = (const float*)d_in[12];
    const float* Wk = (const float*)d_in[13]; const float* bk = (const float*)d_in[14];
    const float* Wv = (const float*)d_in[15]; const float* bv = (const float*)d_in[16];
    const float* Wo = (const float*)d_in[17]; const float* bo = (const float*)d_in[18];
    const float* W_out = (const float*)d_in[19]; const float* b_out = (const float*)d_in[20];

    float* out = (float*)d_out;
    float* out_imputed = out;                 // [B,T,F]
    float* out_stoch   = out + 524288;        // [B,T,F]
    float* out_attn    = out + 1048576;       // [B,T,T]

    float* ws = (float*)d_ws;
    unsigned short* safe_bf = (unsigned short*)ws;             // bf16 [8192][64]
    unsigned short* WnumWqT = (unsigned short*)(ws + 524288);  // bf16 [256][64]
    unsigned short* WnWoT   = (unsigned short*)(ws + 532480);  // bf16 [64][64]
    unsigned short* WnumB   = (unsigned short*)(ws + 534528);  // bf16 [64][256]
    float* bnq  = ws + 542720;                                 // 256 f32
    float* bfin = ws + 542976;                                 // 64 f32
    unsigned short* probs = (unsigned short*)(ws + 2621440);   // bf16 [128][256][256]
    unsigned long long* sel = (unsigned long long*)(ws + 9961472); // u64 [8192][16]
    unsigned short* Pe    = (unsigned short*)(ws + 15204352);  // bf16 [1024][768] (dead after combo2)
    unsigned short* kvproj = (unsigned short*)(ws + 15204352); // bf16 [8192][512] (over dead Pe)
    unsigned short* pvb   = (unsigned short*)(ws + 17301504);  // bf16 [8192][256]
    unsigned short* WoWoutT = (unsigned short*)(ws + 18350080);// bf16 [64][256]
    float* bocomb = ws + 18358272;                             // 64 f32
    float* bkv    = ws + 18358336;                             // 512 f32
    float* inv_cnt = ws + 18358848;                            // 8192 f32
    unsigned short* WadkvT = (unsigned short*)(ws + 18367040); // bf16 [512][768]
    unsigned short* WadB   = (unsigned short*)(ws + 18563648); // bf16 [768][256]
    unsigned short* PeWaT  = (unsigned short*)(ws + 18661952); // bf16 [512][1024]
    float* pooled = ws + 19398656;
    unsigned long long* mask64 = (unsigned long long*)(ws + 19398912);
    unsigned int* plist = (unsigned int*)(ws + 19415296);

    unsigned short* wT = (unsigned short*)(ws + 19419392);
    unsigned short* WqT   = wT + 212992;         // [256][256]
    unsigned short* WkT   = wT + 278528;         // (WkT,WvT contiguous)
    unsigned short* WvT   = wT + 344064;
    unsigned short* WoT   = wT + 409600;
    unsigned short* WoutT = wT + 475136;         // [64][256]

    // 1. prep
    prep_kernel<<<481, 256, 0, stream>>>(
        Wk, Wv, Wo, W_out, W_ad, Wq, W_num, pair_present,
        WkT, WvT, WoT, WoutT, WadB, WqT, WnumB, plist);
    // 2. combo1
    combo1_kernel<<<3108, 256, 0, stream>>>(
        WoutT, WoT, WoWoutT, WkT, WadB, WadkvT,
        WqT, WnumB, WnumWqT, WnWoT,
        sapE, W_sap, b_sap, pooled,
        batch_data, mask_probs, safe_bf, out_stoch, mask64,
        pair_emb, plist, Pe,
        bo, b_out, W_out, bocomb,
        b_ad, bk, bv, Wk, Wv, bkv);
    // 3. combo2: wbuild | PeWaT | bnq | bfin
    combo2_kernel<<<546, 256, 0, stream>>>(
        mask64, plist, sel, inv_cnt, WadkvT, Pe, PeWaT,
        b_num, pooled, Wq, bq, bnq, W_out, bocomb, bfin);
    // 4. combo3: selkv only
    combo3_kernel<<<512, 256, 0, stream>>>(
        sel, PeWaT, inv_cnt, bkv, kvproj);
    // 5. fused attention (K=64 q projection from safe)
    attn_fused_kernel<<<256, 256, 0, stream>>>(
        safe_bf, WnumWqT, bnq, kvproj, probs, pvb);
    // 6. combo4: meanheads | final
    combo4_kernel<<<1152, 256, 0, stream>>>(
        probs, out_attn, safe_bf, pvb, WnWoT, WoWoutT, bfin, out_imputed);
}